// Round 1
// baseline (906.173 us; speedup 1.0000x reference)
//
#include <hip/hip_runtime.h>
#include <math.h>

#define N_NODESc 100000
#define N_EDGESc 800000
#define E_TOTc   (N_EDGESc + N_NODESc)   // 900000, includes self loops
#define F_INc    128
#define HC1c     256                      // H1*C1
#define NCLSc    40
#define NEG_SLOPEc 0.2f

// ---------------- CSR build ----------------

__global__ void k_init_cnt(int* cnt) {
    int i = blockIdx.x * blockDim.x + threadIdx.x;
    if (i < N_NODESc) cnt[i] = 1;  // 1 = the self loop
}

__global__ void k_count(const int* __restrict__ dst, int* cnt) {
    int e = blockIdx.x * blockDim.x + threadIdx.x;
    if (e < N_EDGESc) atomicAdd(&cnt[dst[e]], 1);
}

__global__ void k_scan1(const int* __restrict__ cnt, int* rowptr, int* bsums) {
    __shared__ int sh[512];
    int tid = threadIdx.x;
    int i = blockIdx.x * 512 + tid;
    int v = (i < N_NODESc) ? cnt[i] : 0;
    sh[tid] = v;
    __syncthreads();
    for (int off = 1; off < 512; off <<= 1) {
        int t = (tid >= off) ? sh[tid - off] : 0;
        __syncthreads();
        sh[tid] += t;
        __syncthreads();
    }
    if (i < N_NODESc) rowptr[i] = sh[tid] - v;   // exclusive within block
    if (tid == 511) bsums[blockIdx.x] = sh[511]; // block total
}

__global__ void k_scan2(int* bsums, int nb) {
    if (blockIdx.x == 0 && threadIdx.x == 0) {
        int run = 0;
        for (int b = 0; b < nb; b++) { int t = bsums[b]; bsums[b] = run; run += t; }
    }
}

__global__ void k_scan3(int* rowptr, const int* __restrict__ bsums, int* cursor) {
    int i = blockIdx.x * blockDim.x + threadIdx.x;
    if (i < N_NODESc) {
        int rp = rowptr[i] + bsums[i >> 9];
        rowptr[i] = rp;
        cursor[i] = rp;
    }
    if (i == 0) rowptr[N_NODESc] = E_TOTc;
}

__global__ void k_scatter(const int* __restrict__ src, const int* __restrict__ dst,
                          int* cursor, int* csr) {
    int t = blockIdx.x * blockDim.x + threadIdx.x;
    if (t < N_EDGESc) {
        int pos = atomicAdd(&cursor[dst[t]], 1);
        csr[pos] = src[t];
    } else if (t < E_TOTc) {
        int n = t - N_EDGESc;                   // self loop n -> n
        int pos = atomicAdd(&cursor[n], 1);
        csr[pos] = n;
    }
}

// ---------------- Layer 1 GEMM: h1 = x @ W1, + alpha reductions ----------------
// 8 rows per 256-thread block; thread t owns output column t.

__global__ __launch_bounds__(256) void k_gemm1(
    const float* __restrict__ x, const float* __restrict__ W1,
    const float* __restrict__ a_src1, const float* __restrict__ a_dst1,
    float* __restrict__ h1, float* __restrict__ as1, float* __restrict__ ad1) {
    __shared__ float xs[8][F_INc];
    __shared__ float hsh[8][HC1c];
    int t = threadIdx.x;
    int n0 = blockIdx.x * 8;
    for (int i = t; i < 8 * F_INc; i += 256) {
        int r = i >> 7, k = i & 127;
        int n = n0 + r;
        xs[r][k] = (n < N_NODESc) ? x[(size_t)n * F_INc + k] : 0.f;
    }
    __syncthreads();
    float acc[8] = {0,0,0,0,0,0,0,0};
    for (int k = 0; k < F_INc; k++) {
        float wv = W1[k * HC1c + t];
        #pragma unroll
        for (int r = 0; r < 8; r++) acc[r] += xs[r][k] * wv;
    }
    #pragma unroll
    for (int r = 0; r < 8; r++) {
        hsh[r][t] = acc[r];
        int n = n0 + r;
        if (n < N_NODESc) h1[(size_t)n * HC1c + t] = acc[r];
    }
    __syncthreads();
    if (t < 64) {
        int r = t >> 3, h = t & 7;
        int n = n0 + r;
        if (n < N_NODESc) {
            float s = 0.f, d = 0.f;
            for (int c = 0; c < 32; c++) {
                float v = hsh[r][h * 32 + c];
                s += v * a_src1[h * 32 + c];
                d += v * a_dst1[h * 32 + c];
            }
            as1[n * 8 + h] = s;
            ad1[n * 8 + h] = d;
        }
    }
}

// ---------------- Layer 1 aggregation: online segment softmax + ELU ----------------
// One block (256 thr) per destination node; thread t = head(t/32), ch(t%32).

#define CHUNK1 32
__global__ __launch_bounds__(256) void k_agg1(
    const int* __restrict__ rowptr, const int* __restrict__ csr,
    const float* __restrict__ as1, const float* __restrict__ ad1,
    const float* __restrict__ h1, const float* __restrict__ b1,
    float* __restrict__ act1) {
    int n = blockIdx.x, t = threadIdx.x;
    int beg = rowptr[n], end = rowptr[n + 1];
    __shared__ float w[CHUNK1][8];
    __shared__ int   srcs[CHUNK1];
    __shared__ float mrun[8], drun[8], scl[8];
    if (t < 8) { mrun[t] = -INFINITY; drun[t] = 0.f; }
    int h = t >> 5;
    float ad = ad1[n * 8 + (t & 7)];   // valid for phase-1 threads (t<8)
    float acc = 0.f;
    __syncthreads();
    for (int base = beg; base < end; base += CHUNK1) {
        int m = min(CHUNK1, end - base);
        if (t < m) srcs[t] = csr[base + t];
        __syncthreads();
        if (t < 8) {
            float mold = mrun[t], mc = mold;
            for (int e = 0; e < m; e++) {
                float s = as1[srcs[e] * 8 + t] + ad;
                s = (s > 0.f) ? s : NEG_SLOPEc * s;
                w[e][t] = s;
                mc = fmaxf(mc, s);
            }
            float sc = expf(mold - mc);     // exp(-inf)=0 on first chunk
            float dn = drun[t] * sc;
            for (int e = 0; e < m; e++) {
                float we = expf(w[e][t] - mc);
                w[e][t] = we;
                dn += we;
            }
            mrun[t] = mc; drun[t] = dn; scl[t] = sc;
        }
        __syncthreads();
        float a = acc * scl[h];
        for (int e = 0; e < m; e++)
            a += w[e][h] * h1[(size_t)srcs[e] * HC1c + t];
        acc = a;
        __syncthreads();
    }
    float v = acc / (drun[h] + 1e-16f) + b1[t];
    v = (v > 0.f) ? v : expm1f(v);          // ELU
    act1[(size_t)n * HC1c + t] = v;
}

// ---------------- Layer 2 GEMM: h2 = act1 @ W2, + alpha reductions ----------------
// W2 (256x40 = 40 KB) staged in LDS; 6 rows per block, thread t -> (r=t/40, j=t%40).

__global__ __launch_bounds__(256) void k_gemm2(
    const float* __restrict__ act1, const float* __restrict__ W2,
    const float* __restrict__ a_src2, const float* __restrict__ a_dst2,
    float* __restrict__ h2, float* __restrict__ as2, float* __restrict__ ad2) {
    __shared__ float w2s[HC1c * NCLSc];
    __shared__ float as_[6][HC1c];
    __shared__ float h2sh[6][NCLSc];
    int t = threadIdx.x;
    for (int i = t; i < HC1c * NCLSc; i += 256) w2s[i] = W2[i];
    int n0 = blockIdx.x * 6;
    for (int i = t; i < 6 * HC1c; i += 256) {
        int r = i >> 8, k = i & 255;
        int n = n0 + r;
        as_[r][k] = (n < N_NODESc) ? act1[(size_t)n * HC1c + k] : 0.f;
    }
    __syncthreads();
    if (t < 240) {
        int r = t / NCLSc, j = t % NCLSc;
        float acc = 0.f;
        for (int k = 0; k < HC1c; k++) acc += as_[r][k] * w2s[k * NCLSc + j];
        int n = n0 + r;
        if (n < N_NODESc) h2[(size_t)n * NCLSc + j] = acc;
        h2sh[r][j] = acc;
    }
    __syncthreads();
    if (t < 6) {
        int n = n0 + t;
        if (n < N_NODESc) {
            float s = 0.f, d = 0.f;
            for (int j = 0; j < NCLSc; j++) {
                float v = h2sh[t][j];
                s += v * a_src2[j];
                d += v * a_dst2[j];
            }
            as2[n] = s;
            ad2[n] = d;
        }
    }
}

// ---------------- Layer 2 aggregation + bias + log_softmax ----------------
// One wave (64 thr) per node.

#define CHUNK2 64
__global__ __launch_bounds__(64) void k_agg2(
    const int* __restrict__ rowptr, const int* __restrict__ csr,
    const float* __restrict__ as2, const float* __restrict__ ad2,
    const float* __restrict__ h2, const float* __restrict__ b2,
    float* __restrict__ out) {
    int n = blockIdx.x, t = threadIdx.x;
    int beg = rowptr[n], end = rowptr[n + 1];
    __shared__ float w[CHUNK2];
    __shared__ int   srcs[CHUNK2];
    __shared__ float mrun1, drun1, scl1;
    __shared__ float vals[NCLSc];
    if (t == 0) { mrun1 = -INFINITY; drun1 = 0.f; }
    float ad = ad2[n];
    float acc = 0.f;
    __syncthreads();
    for (int base = beg; base < end; base += CHUNK2) {
        int m = min(CHUNK2, end - base);
        if (t < m) srcs[t] = csr[base + t];
        __syncthreads();
        if (t == 0) {
            float mold = mrun1, mc = mold;
            for (int e = 0; e < m; e++) {
                float s = as2[srcs[e]] + ad;
                s = (s > 0.f) ? s : NEG_SLOPEc * s;
                w[e] = s;
                mc = fmaxf(mc, s);
            }
            float sc = expf(mold - mc);
            float dn = drun1 * sc;
            for (int e = 0; e < m; e++) {
                float we = expf(w[e] - mc);
                w[e] = we;
                dn += we;
            }
            mrun1 = mc; drun1 = dn; scl1 = sc;
        }
        __syncthreads();
        if (t < NCLSc) {
            float a = acc * scl1;
            for (int e = 0; e < m; e++)
                a += w[e] * h2[(size_t)srcs[e] * NCLSc + t];
            acc = a;
        }
        __syncthreads();
    }
    if (t < NCLSc) vals[t] = acc / (drun1 + 1e-16f) + b2[t];
    __syncthreads();
    if (t == 0) {
        float mx = -INFINITY;
        for (int j = 0; j < NCLSc; j++) mx = fmaxf(mx, vals[j]);
        float s = 0.f;
        for (int j = 0; j < NCLSc; j++) s += expf(vals[j] - mx);
        mrun1 = mx; drun1 = logf(s);
    }
    __syncthreads();
    if (t < NCLSc) out[(size_t)n * NCLSc + t] = vals[t] - mrun1 - drun1;
}

// ---------------- launch ----------------

extern "C" void kernel_launch(void* const* d_in, const int* in_sizes, int n_in,
                              void* d_out, int out_size, void* d_ws, size_t ws_size,
                              hipStream_t stream) {
    const float* x    = (const float*)d_in[0];
    const int*   ei   = (const int*)d_in[1];     // [2, E] int32
    const float* W1   = (const float*)d_in[2];
    const float* as1w = (const float*)d_in[3];
    const float* ad1w = (const float*)d_in[4];
    const float* b1   = (const float*)d_in[5];
    const float* W2   = (const float*)d_in[6];
    const float* as2w = (const float*)d_in[7];
    const float* ad2w = (const float*)d_in[8];
    const float* b2   = (const float*)d_in[9];
    float* out = (float*)d_out;

    char* p = (char*)d_ws;
    float* h1   = (float*)p; p += (size_t)N_NODESc * HC1c * 4;
    float* act1 = (float*)p; p += (size_t)N_NODESc * HC1c * 4;
    float* a_s1 = (float*)p; p += (size_t)N_NODESc * 8 * 4;
    float* a_d1 = (float*)p; p += (size_t)N_NODESc * 8 * 4;
    float* h2   = (float*)p; p += (size_t)N_NODESc * NCLSc * 4;
    float* a_s2 = (float*)p; p += (size_t)N_NODESc * 4;
    float* a_d2 = (float*)p; p += (size_t)N_NODESc * 4;
    int* rowptr = (int*)p;   p += (size_t)(N_NODESc + 1) * 4;
    int* cursor = (int*)p;   p += (size_t)N_NODESc * 4;
    int* bsums  = (int*)p;   p += 256 * 4;
    int* csr    = (int*)p;   p += (size_t)E_TOTc * 4;
    (void)ws_size; (void)in_sizes; (void)n_in; (void)out_size;

    const int* src = ei;
    const int* dst = ei + N_EDGESc;

    k_init_cnt<<<(N_NODESc + 255) / 256, 256, 0, stream>>>(cursor);
    k_count<<<(N_EDGESc + 255) / 256, 256, 0, stream>>>(dst, cursor);
    int nb = (N_NODESc + 511) / 512;
    k_scan1<<<nb, 512, 0, stream>>>(cursor, rowptr, bsums);
    k_scan2<<<1, 64, 0, stream>>>(bsums, nb);
    k_scan3<<<(N_NODESc + 255) / 256, 256, 0, stream>>>(rowptr, bsums, cursor);
    k_scatter<<<(E_TOTc + 255) / 256, 256, 0, stream>>>(src, dst, cursor, csr);

    k_gemm1<<<(N_NODESc + 7) / 8, 256, 0, stream>>>(x, W1, as1w, ad1w, h1, a_s1, a_d1);
    k_agg1<<<N_NODESc, 256, 0, stream>>>(rowptr, csr, a_s1, a_d1, h1, b1, act1);
    k_gemm2<<<(N_NODESc + 5) / 6, 256, 0, stream>>>(act1, W2, as2w, ad2w, h2, a_s2, a_d2);
    k_agg2<<<N_NODESc, 64, 0, stream>>>(rowptr, csr, a_s2, a_d2, h2, b2, out);
}

// Round 2
// 710.405 us; speedup vs baseline: 1.2756x; 1.2756x over previous
//
#include <hip/hip_runtime.h>
#include <hip/hip_bf16.h>
#include <math.h>

#define N_NODESc 100000
#define N_EDGESc 800000
#define E_TOTc   (N_EDGESc + N_NODESc)   // 900000, includes self loops
#define F_INc    128
#define HC1c     256                      // H1*C1
#define NCLSc    40
#define NEG_SLOPEc 0.2f

// ---------------- CSR build ----------------

__global__ void k_init_cnt(int* cnt) {
    int i = blockIdx.x * blockDim.x + threadIdx.x;
    if (i < N_NODESc) cnt[i] = 1;  // 1 = the self loop
}

__global__ void k_count(const int* __restrict__ dst, int* cnt) {
    int e = blockIdx.x * blockDim.x + threadIdx.x;
    if (e < N_EDGESc) atomicAdd(&cnt[dst[e]], 1);
}

__global__ void k_scan1(const int* __restrict__ cnt, int* rowptr, int* bsums) {
    __shared__ int sh[512];
    int tid = threadIdx.x;
    int i = blockIdx.x * 512 + tid;
    int v = (i < N_NODESc) ? cnt[i] : 0;
    sh[tid] = v;
    __syncthreads();
    for (int off = 1; off < 512; off <<= 1) {
        int t = (tid >= off) ? sh[tid - off] : 0;
        __syncthreads();
        sh[tid] += t;
        __syncthreads();
    }
    if (i < N_NODESc) rowptr[i] = sh[tid] - v;   // exclusive within block
    if (tid == 511) bsums[blockIdx.x] = sh[511]; // block total
}

__global__ void k_scan2(int* bsums, int nb) {
    if (blockIdx.x == 0 && threadIdx.x == 0) {
        int run = 0;
        for (int b = 0; b < nb; b++) { int t = bsums[b]; bsums[b] = run; run += t; }
    }
}

__global__ void k_scan3(int* rowptr, const int* __restrict__ bsums, int* cursor) {
    int i = blockIdx.x * blockDim.x + threadIdx.x;
    if (i < N_NODESc) {
        int rp = rowptr[i] + bsums[i >> 9];
        rowptr[i] = rp;
        cursor[i] = rp;
    }
    if (i == 0) rowptr[N_NODESc] = E_TOTc;
}

__global__ void k_scatter(const int* __restrict__ src, const int* __restrict__ dst,
                          int* cursor, int* csr) {
    int t = blockIdx.x * blockDim.x + threadIdx.x;
    if (t < N_EDGESc) {
        int pos = atomicAdd(&cursor[dst[t]], 1);
        csr[pos] = src[t];
    } else if (t < E_TOTc) {
        int n = t - N_EDGESc;                   // self loop n -> n
        int pos = atomicAdd(&cursor[n], 1);
        csr[pos] = n;
    }
}

// ---------------- Layer 1 GEMM: h1 = x @ W1 (bf16 out), + alpha reductions ----

__global__ __launch_bounds__(256) void k_gemm1(
    const float* __restrict__ x, const float* __restrict__ W1,
    const float* __restrict__ a_src1, const float* __restrict__ a_dst1,
    __hip_bfloat16* __restrict__ h1, float* __restrict__ as1, float* __restrict__ ad1) {
    __shared__ float xs[8][F_INc];
    __shared__ float hsh[8][HC1c];
    int t = threadIdx.x;
    int n0 = blockIdx.x * 8;
    for (int i = t; i < 8 * F_INc; i += 256) {
        int r = i >> 7, k = i & 127;
        int n = n0 + r;
        xs[r][k] = (n < N_NODESc) ? x[(size_t)n * F_INc + k] : 0.f;
    }
    __syncthreads();
    float acc[8] = {0,0,0,0,0,0,0,0};
    for (int k = 0; k < F_INc; k++) {
        float wv = W1[k * HC1c + t];
        #pragma unroll
        for (int r = 0; r < 8; r++) acc[r] += xs[r][k] * wv;
    }
    #pragma unroll
    for (int r = 0; r < 8; r++) {
        hsh[r][t] = acc[r];
        int n = n0 + r;
        if (n < N_NODESc) h1[(size_t)n * HC1c + t] = __float2bfloat16(acc[r]);
    }
    __syncthreads();
    if (t < 64) {
        int r = t >> 3, h = t & 7;
        int n = n0 + r;
        if (n < N_NODESc) {
            float s = 0.f, d = 0.f;
            for (int c = 0; c < 32; c++) {
                float v = hsh[r][h * 32 + c];
                s += v * a_src1[h * 32 + c];
                d += v * a_dst1[h * 32 + c];
            }
            as1[n * 8 + h] = s;
            ad1[n * 8 + h] = d;
        }
    }
}

// ---------------- Layer 1 aggregation: wave-per-node, shuffle softmax, bf16 gather
// Lane L: phase-1 role (eL = L>>3, hL = L&7); accumulation role: head H = L>>3,
// channels 4L..4L+3 (float4 of the 256-wide row).

__global__ __launch_bounds__(256) void k_agg1(
    const int* __restrict__ rowptr, const int* __restrict__ csr,
    const float* __restrict__ as1, const float* __restrict__ ad1,
    const __hip_bfloat16* __restrict__ h1, const float* __restrict__ b1,
    float* __restrict__ act1) {
    int n = blockIdx.x * 4 + (threadIdx.x >> 6);
    if (n >= N_NODESc) return;
    int L = threadIdx.x & 63;
    int eL = L >> 3, hL = L & 7;
    int H = L >> 3;                       // head for accumulation role
    int beg = rowptr[n], end = rowptr[n + 1];
    float ad = ad1[n * 8 + hL];
    float m_run = -INFINITY, d_run = 0.f;
    float4 acc = {0.f, 0.f, 0.f, 0.f};
    for (int base = beg; base < end; base += 8) {
        int m = min(8, end - base);
        int src = 0; float s = -INFINITY;
        if (eL < m) {
            src = csr[base + eL];
            float v = as1[src * 8 + hL] + ad;
            s = (v > 0.f) ? v : NEG_SLOPEc * v;
        }
        // per-head chunk max: reduce over lanes with same (L&7)
        float mc = s;
        mc = fmaxf(mc, __shfl_xor(mc, 8));
        mc = fmaxf(mc, __shfl_xor(mc, 16));
        mc = fmaxf(mc, __shfl_xor(mc, 32));
        float mnew = fmaxf(m_run, mc);
        float w = (eL < m) ? __expf(s - mnew) : 0.f;
        float wsum = w;
        wsum += __shfl_xor(wsum, 8);
        wsum += __shfl_xor(wsum, 16);
        wsum += __shfl_xor(wsum, 32);
        float scale = __expf(m_run - mnew);   // first chunk: exp(-inf)=0
        d_run = d_run * scale + wsum;
        m_run = mnew;
        // rescale accumulator by this chunk's scale for my head
        float sc = __shfl(scale, H);          // lane H holds head H state
        acc.x *= sc; acc.y *= sc; acc.z *= sc; acc.w *= sc;
        for (int e = 0; e < m; e++) {
            float we = __shfl(w, e * 8 + H);
            int  se = __shfl(src, e * 8);
            uint2 pk = *((const uint2*)(h1 + (size_t)se * HC1c) + L);
            float v0 = __uint_as_float(pk.x << 16);
            float v1 = __uint_as_float(pk.x & 0xffff0000u);
            float v2 = __uint_as_float(pk.y << 16);
            float v3 = __uint_as_float(pk.y & 0xffff0000u);
            acc.x += we * v0; acc.y += we * v1;
            acc.z += we * v2; acc.w += we * v3;
        }
    }
    float inv = 1.f / (d_run + 1e-16f);
    float inv_h = __shfl(inv, H);
    float4 bb = ((const float4*)b1)[L];
    float4 o;
    o.x = acc.x * inv_h + bb.x;
    o.y = acc.y * inv_h + bb.y;
    o.z = acc.z * inv_h + bb.z;
    o.w = acc.w * inv_h + bb.w;
    o.x = (o.x > 0.f) ? o.x : expm1f(o.x);
    o.y = (o.y > 0.f) ? o.y : expm1f(o.y);
    o.z = (o.z > 0.f) ? o.z : expm1f(o.z);
    o.w = (o.w > 0.f) ? o.w : expm1f(o.w);
    ((float4*)(act1 + (size_t)n * HC1c))[L] = o;
}

// ---------------- Layer 2 GEMM: h2 = act1 @ W2, + alpha reductions ----------------

__global__ __launch_bounds__(256) void k_gemm2(
    const float* __restrict__ act1, const float* __restrict__ W2,
    const float* __restrict__ a_src2, const float* __restrict__ a_dst2,
    float* __restrict__ h2, float* __restrict__ as2, float* __restrict__ ad2) {
    __shared__ float w2s[HC1c * NCLSc];
    __shared__ float as_[6][HC1c];
    __shared__ float h2sh[6][NCLSc];
    int t = threadIdx.x;
    for (int i = t; i < HC1c * NCLSc; i += 256) w2s[i] = W2[i];
    int n0 = blockIdx.x * 6;
    for (int i = t; i < 6 * HC1c; i += 256) {
        int r = i >> 8, k = i & 255;
        int n = n0 + r;
        as_[r][k] = (n < N_NODESc) ? act1[(size_t)n * HC1c + k] : 0.f;
    }
    __syncthreads();
    if (t < 240) {
        int r = t / NCLSc, j = t % NCLSc;
        float acc = 0.f;
        for (int k = 0; k < HC1c; k++) acc += as_[r][k] * w2s[k * NCLSc + j];
        int n = n0 + r;
        if (n < N_NODESc) h2[(size_t)n * NCLSc + j] = acc;
        h2sh[r][j] = acc;
    }
    __syncthreads();
    if (t < 6) {
        int n = n0 + t;
        if (n < N_NODESc) {
            float s = 0.f, d = 0.f;
            for (int j = 0; j < NCLSc; j++) {
                float v = h2sh[t][j];
                s += v * a_src2[j];
                d += v * a_dst2[j];
            }
            as2[n] = s;
            ad2[n] = d;
        }
    }
}

// ---------------- Layer 2 aggregation + bias + log_softmax: wave-per-node ----

__global__ __launch_bounds__(256) void k_agg2(
    const int* __restrict__ rowptr, const int* __restrict__ csr,
    const float* __restrict__ as2, const float* __restrict__ ad2,
    const float* __restrict__ h2, const float* __restrict__ b2,
    float* __restrict__ out) {
    int n = blockIdx.x * 4 + (threadIdx.x >> 6);
    if (n >= N_NODESc) return;
    int L = threadIdx.x & 63;
    int beg = rowptr[n], end = rowptr[n + 1];
    float ad = ad2[n];
    float m_run = -INFINITY, d_run = 0.f, acc = 0.f;
    for (int base = beg; base < end; base += 64) {
        int m = min(64, end - base);
        int src = 0; float s = -INFINITY;
        if (L < m) {
            src = csr[base + L];
            float v = as2[src] + ad;
            s = (v > 0.f) ? v : NEG_SLOPEc * v;
        }
        float mc = s;
        for (int o = 32; o; o >>= 1) mc = fmaxf(mc, __shfl_xor(mc, o));
        float mnew = fmaxf(m_run, mc);
        float w = (L < m) ? __expf(s - mnew) : 0.f;
        float ws = w;
        for (int o = 32; o; o >>= 1) ws += __shfl_xor(ws, o);
        float scale = __expf(m_run - mnew);
        d_run = d_run * scale + ws;
        m_run = mnew;
        acc *= scale;
        for (int e = 0; e < m; e++) {
            float we = __shfl(w, e);
            int  se = __shfl(src, e);
            if (L < NCLSc) acc += we * h2[(size_t)se * NCLSc + L];
        }
    }
    float val = (L < NCLSc) ? acc / (d_run + 1e-16f) + b2[L] : -INFINITY;
    float mx = val;
    for (int o = 32; o; o >>= 1) mx = fmaxf(mx, __shfl_xor(mx, o));
    float ex = (L < NCLSc) ? __expf(val - mx) : 0.f;
    float ssum = ex;
    for (int o = 32; o; o >>= 1) ssum += __shfl_xor(ssum, o);
    float ls = logf(ssum);
    if (L < NCLSc) out[(size_t)n * NCLSc + L] = val - mx - ls;
}

// ---------------- launch ----------------

extern "C" void kernel_launch(void* const* d_in, const int* in_sizes, int n_in,
                              void* d_out, int out_size, void* d_ws, size_t ws_size,
                              hipStream_t stream) {
    const float* x    = (const float*)d_in[0];
    const int*   ei   = (const int*)d_in[1];     // [2, E] int32
    const float* W1   = (const float*)d_in[2];
    const float* as1w = (const float*)d_in[3];
    const float* ad1w = (const float*)d_in[4];
    const float* b1   = (const float*)d_in[5];
    const float* W2   = (const float*)d_in[6];
    const float* as2w = (const float*)d_in[7];
    const float* ad2w = (const float*)d_in[8];
    const float* b2   = (const float*)d_in[9];
    float* out = (float*)d_out;

    char* p = (char*)d_ws;
    __hip_bfloat16* h1 = (__hip_bfloat16*)p; p += (size_t)N_NODESc * HC1c * 2;
    float* act1 = (float*)p; p += (size_t)N_NODESc * HC1c * 4;
    float* a_s1 = (float*)p; p += (size_t)N_NODESc * 8 * 4;
    float* a_d1 = (float*)p; p += (size_t)N_NODESc * 8 * 4;
    float* h2   = (float*)p; p += (size_t)N_NODESc * NCLSc * 4;
    float* a_s2 = (float*)p; p += (size_t)N_NODESc * 4;
    float* a_d2 = (float*)p; p += (size_t)N_NODESc * 4;
    int* rowptr = (int*)p;   p += (size_t)(N_NODESc + 1) * 4;
    int* cursor = (int*)p;   p += (size_t)N_NODESc * 4;
    int* bsums  = (int*)p;   p += 256 * 4;
    int* csr    = (int*)p;   p += (size_t)E_TOTc * 4;
    (void)ws_size; (void)in_sizes; (void)n_in; (void)out_size;

    const int* src = ei;
    const int* dst = ei + N_EDGESc;

    k_init_cnt<<<(N_NODESc + 255) / 256, 256, 0, stream>>>(cursor);
    k_count<<<(N_EDGESc + 255) / 256, 256, 0, stream>>>(dst, cursor);
    int nb = (N_NODESc + 511) / 512;
    k_scan1<<<nb, 512, 0, stream>>>(cursor, rowptr, bsums);
    k_scan2<<<1, 64, 0, stream>>>(bsums, nb);
    k_scan3<<<(N_NODESc + 255) / 256, 256, 0, stream>>>(rowptr, bsums, cursor);
    k_scatter<<<(E_TOTc + 255) / 256, 256, 0, stream>>>(src, dst, cursor, csr);

    k_gemm1<<<(N_NODESc + 7) / 8, 256, 0, stream>>>(x, W1, as1w, ad1w, h1, a_s1, a_d1);
    k_agg1<<<(N_NODESc + 3) / 4, 256, 0, stream>>>(rowptr, csr, a_s1, a_d1, h1, b1, act1);
    k_gemm2<<<(N_NODESc + 5) / 6, 256, 0, stream>>>(act1, W2, as2w, ad2w, h2, a_s2, a_d2);
    k_agg2<<<(N_NODESc + 3) / 4, 256, 0, stream>>>(rowptr, csr, a_s2, a_d2, h2, b2, out);
}

// Round 3
// 535.824 us; speedup vs baseline: 1.6912x; 1.3258x over previous
//
#include <hip/hip_runtime.h>
#include <hip/hip_bf16.h>
#include <math.h>

#define N_NODESc 100000
#define N_EDGESc 800000
#define E_TOTc   (N_EDGESc + N_NODESc)   // 900000, includes self loops
#define F_INc    128
#define HC1c     256                      // H1*C1
#define NCLSc    40
#define NCLSPc   48                       // padded to 3x16
#define NEG_SLOPEc 0.2f

typedef __attribute__((ext_vector_type(8))) short short8;   // 8 bf16 (4 VGPRs)
typedef __attribute__((ext_vector_type(4))) float f32x4;

__device__ __forceinline__ unsigned bfpack(float a, float b) {
    unsigned ua = __float_as_uint(a), ub = __float_as_uint(b);
    ua += 0x7fff + ((ua >> 16) & 1);      // RNE
    ub += 0x7fff + ((ub >> 16) & 1);
    return (ua >> 16) | (ub & 0xffff0000u);
}

// ---------------- CSR build ----------------

__global__ void k_init_cnt(int* cnt) {
    int i = blockIdx.x * blockDim.x + threadIdx.x;
    if (i < N_NODESc) cnt[i] = 1;  // 1 = the self loop
}

__global__ void k_count(const int* __restrict__ dst, int* cnt) {
    int e = blockIdx.x * blockDim.x + threadIdx.x;
    if (e < N_EDGESc) atomicAdd(&cnt[dst[e]], 1);
}

__global__ void k_scan1(const int* __restrict__ cnt, int* rowptr, int* bsums) {
    __shared__ int sh[512];
    int tid = threadIdx.x;
    int i = blockIdx.x * 512 + tid;
    int v = (i < N_NODESc) ? cnt[i] : 0;
    sh[tid] = v;
    __syncthreads();
    for (int off = 1; off < 512; off <<= 1) {
        int t = (tid >= off) ? sh[tid - off] : 0;
        __syncthreads();
        sh[tid] += t;
        __syncthreads();
    }
    if (i < N_NODESc) rowptr[i] = sh[tid] - v;
    if (tid == 511) bsums[blockIdx.x] = sh[511];
}

__global__ void k_scan2(int* bsums, int nb) {
    if (blockIdx.x == 0 && threadIdx.x == 0) {
        int run = 0;
        for (int b = 0; b < nb; b++) { int t = bsums[b]; bsums[b] = run; run += t; }
    }
}

__global__ void k_scan3(int* rowptr, const int* __restrict__ bsums, int* cursor) {
    int i = blockIdx.x * blockDim.x + threadIdx.x;
    if (i < N_NODESc) {
        int rp = rowptr[i] + bsums[i >> 9];
        rowptr[i] = rp;
        cursor[i] = rp;
    }
    if (i == 0) rowptr[N_NODESc] = E_TOTc;
}

__global__ void k_scatter(const int* __restrict__ src, const int* __restrict__ dst,
                          int* cursor, int* csr) {
    int t = blockIdx.x * blockDim.x + threadIdx.x;
    if (t < N_EDGESc) {
        int pos = atomicAdd(&cursor[dst[t]], 1);
        csr[pos] = src[t];
    } else if (t < E_TOTc) {
        int n = t - N_EDGESc;
        int pos = atomicAdd(&cursor[n], 1);
        csr[pos] = n;
    }
}

// ---------------- prep: x -> bf16, W1^T/W2^T -> bf16 ----------------

__global__ void k_castx(const float* __restrict__ x, unsigned* __restrict__ xb) {
    int i = blockIdx.x * 256 + threadIdx.x;                 // one float4 per thread
    if (i >= N_NODESc * F_INc / 4) return;
    float4 v = ((const float4*)x)[i];
    uint2 o; o.x = bfpack(v.x, v.y); o.y = bfpack(v.z, v.w);
    ((uint2*)xb)[i] = o;
}

__global__ void k_prepw(const float* __restrict__ W1, const float* __restrict__ W2,
                        __hip_bfloat16* __restrict__ W1T, __hip_bfloat16* __restrict__ W2T) {
    int i = blockIdx.x * 256 + threadIdx.x;
    if (i < HC1c * F_INc) {                                  // W1T[c][k], c<256,k<128
        int c = i >> 7, k = i & 127;
        W1T[i] = __float2bfloat16(W1[k * HC1c + c]);
    } else {
        int j = i - HC1c * F_INc;
        if (j < NCLSPc * HC1c) {                             // W2T[c][k], c<48,k<256
            int c = j >> 8, k = j & 255;
            W2T[j] = (c < NCLSc) ? __float2bfloat16(W2[k * NCLSc + c]) : __float2bfloat16(0.f);
        }
    }
}

// ---------------- Layer 1 GEMM (MFMA, no LDS): h1 = xb @ W1 (bf16 out) --------
// Wave computes 16 nodes x 256 cols; A frag = xb row chunk, B frag = W1T row chunk.

__global__ __launch_bounds__(256) void k_gemm1(
    const __hip_bfloat16* __restrict__ xb, const __hip_bfloat16* __restrict__ W1T,
    __hip_bfloat16* __restrict__ h1) {
    int wave = (blockIdx.x * 256 + threadIdx.x) >> 6;
    int n0 = wave * 16;
    if (n0 >= N_NODESc) return;
    int L = threadIdx.x & 63, lane16 = L & 15, quad = L >> 4;
    f32x4 acc[16];
    #pragma unroll
    for (int jt = 0; jt < 16; jt++) acc[jt] = (f32x4){0.f, 0.f, 0.f, 0.f};
    const short* A = (const short*)xb + (size_t)(n0 + lane16) * F_INc + quad * 8;
    const short* B = (const short*)W1T + lane16 * F_INc + quad * 8;
    #pragma unroll
    for (int k0 = 0; k0 < 4; k0++) {                         // K = 4 x 32
        short8 af = *(const short8*)(A + k0 * 32);
        #pragma unroll
        for (int jt = 0; jt < 16; jt++) {
            short8 bf = *(const short8*)(B + jt * 16 * F_INc + k0 * 32);
            acc[jt] = __builtin_amdgcn_mfma_f32_16x16x32_bf16(af, bf, acc[jt], 0, 0, 0);
        }
    }
    // D[row = quad*4+r][col = jt*16+lane16]
    #pragma unroll
    for (int jt = 0; jt < 16; jt++) {
        #pragma unroll
        for (int r = 0; r < 4; r++) {
            int n = n0 + quad * 4 + r;
            h1[(size_t)n * HC1c + jt * 16 + lane16] = __float2bfloat16(acc[jt][r]);
        }
    }
}

// ---------------- alpha1: as1/ad1 from bf16 h1 ----------------

__global__ __launch_bounds__(256) void k_alpha1(
    const __hip_bfloat16* __restrict__ h1, const float* __restrict__ a_src1,
    const float* __restrict__ a_dst1, float* __restrict__ as1, float* __restrict__ ad1) {
    int i = blockIdx.x * 256 + threadIdx.x;                  // (n, h)
    if (i >= N_NODESc * 8) return;
    int n = i >> 3, h = i & 7;
    const uint4* p = (const uint4*)((const unsigned short*)h1 + (size_t)n * HC1c + h * 32);
    float s = 0.f, d = 0.f;
    #pragma unroll
    for (int q = 0; q < 4; q++) {                            // 4 x 8 bf16 = 32 ch
        uint4 pk = p[q];
        int c = h * 32 + q * 8;
        float v[8];
        v[0] = __uint_as_float(pk.x << 16); v[1] = __uint_as_float(pk.x & 0xffff0000u);
        v[2] = __uint_as_float(pk.y << 16); v[3] = __uint_as_float(pk.y & 0xffff0000u);
        v[4] = __uint_as_float(pk.z << 16); v[5] = __uint_as_float(pk.z & 0xffff0000u);
        v[6] = __uint_as_float(pk.w << 16); v[7] = __uint_as_float(pk.w & 0xffff0000u);
        #pragma unroll
        for (int j = 0; j < 8; j++) {
            s += v[j] * a_src1[c + j];
            d += v[j] * a_dst1[c + j];
        }
    }
    as1[i] = s;
    ad1[i] = d;
}

// ---------------- Layer 1 aggregation: wave-per-node, shuffle softmax ----------

__global__ __launch_bounds__(256) void k_agg1(
    const int* __restrict__ rowptr, const int* __restrict__ csr,
    const float* __restrict__ as1, const float* __restrict__ ad1,
    const __hip_bfloat16* __restrict__ h1, const float* __restrict__ b1,
    __hip_bfloat16* __restrict__ act1b) {
    int n = blockIdx.x * 4 + (threadIdx.x >> 6);
    if (n >= N_NODESc) return;
    int L = threadIdx.x & 63;
    int eL = L >> 3, hL = L & 7;
    int H = L >> 3;
    int beg = rowptr[n], end = rowptr[n + 1];
    float ad = ad1[n * 8 + hL];
    float m_run = -INFINITY, d_run = 0.f;
    float4 acc = {0.f, 0.f, 0.f, 0.f};
    for (int base = beg; base < end; base += 8) {
        int m = min(8, end - base);
        int src = 0; float s = -INFINITY;
        if (eL < m) {
            src = csr[base + eL];
            float v = as1[src * 8 + hL] + ad;
            s = (v > 0.f) ? v : NEG_SLOPEc * v;
        }
        float mc = s;
        mc = fmaxf(mc, __shfl_xor(mc, 8));
        mc = fmaxf(mc, __shfl_xor(mc, 16));
        mc = fmaxf(mc, __shfl_xor(mc, 32));
        float mnew = fmaxf(m_run, mc);
        float w = (eL < m) ? __expf(s - mnew) : 0.f;
        float wsum = w;
        wsum += __shfl_xor(wsum, 8);
        wsum += __shfl_xor(wsum, 16);
        wsum += __shfl_xor(wsum, 32);
        float scale = __expf(m_run - mnew);
        d_run = d_run * scale + wsum;
        m_run = mnew;
        float sc = __shfl(scale, H);
        acc.x *= sc; acc.y *= sc; acc.z *= sc; acc.w *= sc;
        for (int e = 0; e < m; e++) {
            float we = __shfl(w, e * 8 + H);
            int  se = __shfl(src, e * 8);
            uint2 pk = *((const uint2*)(h1 + (size_t)se * HC1c) + L);
            acc.x += we * __uint_as_float(pk.x << 16);
            acc.y += we * __uint_as_float(pk.x & 0xffff0000u);
            acc.z += we * __uint_as_float(pk.y << 16);
            acc.w += we * __uint_as_float(pk.y & 0xffff0000u);
        }
    }
    float inv = 1.f / (d_run + 1e-16f);
    float inv_h = __shfl(inv, H);
    float4 bb = ((const float4*)b1)[L];
    float4 o;
    o.x = acc.x * inv_h + bb.x;
    o.y = acc.y * inv_h + bb.y;
    o.z = acc.z * inv_h + bb.z;
    o.w = acc.w * inv_h + bb.w;
    o.x = (o.x > 0.f) ? o.x : expm1f(o.x);
    o.y = (o.y > 0.f) ? o.y : expm1f(o.y);
    o.z = (o.z > 0.f) ? o.z : expm1f(o.z);
    o.w = (o.w > 0.f) ? o.w : expm1f(o.w);
    uint2 st; st.x = bfpack(o.x, o.y); st.y = bfpack(o.z, o.w);
    ((uint2*)((unsigned short*)act1b + (size_t)n * HC1c))[L] = st;
}

// ---------------- Layer 2 GEMM (MFMA, no LDS) + fused alpha2 ----------------

__global__ __launch_bounds__(256) void k_gemm2(
    const __hip_bfloat16* __restrict__ act1b, const __hip_bfloat16* __restrict__ W2T,
    const float* __restrict__ a_src2, const float* __restrict__ a_dst2,
    float* __restrict__ h2, float* __restrict__ as2, float* __restrict__ ad2) {
    int wave = (blockIdx.x * 256 + threadIdx.x) >> 6;
    int n0 = wave * 16;
    if (n0 >= N_NODESc) return;
    int L = threadIdx.x & 63, lane16 = L & 15, quad = L >> 4;
    f32x4 acc[3];
    #pragma unroll
    for (int jt = 0; jt < 3; jt++) acc[jt] = (f32x4){0.f, 0.f, 0.f, 0.f};
    const short* A = (const short*)act1b + (size_t)(n0 + lane16) * HC1c + quad * 8;
    const short* B = (const short*)W2T + lane16 * HC1c + quad * 8;
    #pragma unroll
    for (int k0 = 0; k0 < 8; k0++) {                         // K = 8 x 32
        short8 af = *(const short8*)(A + k0 * 32);
        #pragma unroll
        for (int jt = 0; jt < 3; jt++) {
            short8 bf = *(const short8*)(B + jt * 16 * HC1c + k0 * 32);
            acc[jt] = __builtin_amdgcn_mfma_f32_16x16x32_bf16(af, bf, acc[jt], 0, 0, 0);
        }
    }
    float ps[4] = {0.f, 0.f, 0.f, 0.f}, pd[4] = {0.f, 0.f, 0.f, 0.f};
    #pragma unroll
    for (int jt = 0; jt < 3; jt++) {
        int col = jt * 16 + lane16;
        float ws = (col < NCLSc) ? a_src2[col] : 0.f;
        float wd = (col < NCLSc) ? a_dst2[col] : 0.f;
        #pragma unroll
        for (int r = 0; r < 4; r++) {
            float v = acc[jt][r];
            int n = n0 + quad * 4 + r;
            if (col < NCLSc) h2[(size_t)n * NCLSc + col] = v;
            ps[r] += v * ws; pd[r] += v * wd;
        }
    }
    #pragma unroll
    for (int r = 0; r < 4; r++) {
        float s = ps[r], d = pd[r];
        s += __shfl_xor(s, 1); d += __shfl_xor(d, 1);
        s += __shfl_xor(s, 2); d += __shfl_xor(d, 2);
        s += __shfl_xor(s, 4); d += __shfl_xor(d, 4);
        s += __shfl_xor(s, 8); d += __shfl_xor(d, 8);
        if (lane16 == 0) {
            int n = n0 + quad * 4 + r;
            as2[n] = s; ad2[n] = d;
        }
    }
}

// ---------------- Layer 2 aggregation + bias + log_softmax: wave-per-node ----

__global__ __launch_bounds__(256) void k_agg2(
    const int* __restrict__ rowptr, const int* __restrict__ csr,
    const float* __restrict__ as2, const float* __restrict__ ad2,
    const float* __restrict__ h2, const float* __restrict__ b2,
    float* __restrict__ out) {
    int n = blockIdx.x * 4 + (threadIdx.x >> 6);
    if (n >= N_NODESc) return;
    int L = threadIdx.x & 63;
    int beg = rowptr[n], end = rowptr[n + 1];
    float ad = ad2[n];
    float m_run = -INFINITY, d_run = 0.f, acc = 0.f;
    for (int base = beg; base < end; base += 64) {
        int m = min(64, end - base);
        int src = 0; float s = -INFINITY;
        if (L < m) {
            src = csr[base + L];
            float v = as2[src] + ad;
            s = (v > 0.f) ? v : NEG_SLOPEc * v;
        }
        float mc = s;
        for (int o = 32; o; o >>= 1) mc = fmaxf(mc, __shfl_xor(mc, o));
        float mnew = fmaxf(m_run, mc);
        float w = (L < m) ? __expf(s - mnew) : 0.f;
        float ws = w;
        for (int o = 32; o; o >>= 1) ws += __shfl_xor(ws, o);
        float scale = __expf(m_run - mnew);
        d_run = d_run * scale + ws;
        m_run = mnew;
        acc *= scale;
        for (int e = 0; e < m; e++) {
            float we = __shfl(w, e);
            int  se = __shfl(src, e);
            if (L < NCLSc) acc += we * h2[(size_t)se * NCLSc + L];
        }
    }
    float val = (L < NCLSc) ? acc / (d_run + 1e-16f) + b2[L] : -INFINITY;
    float mx = val;
    for (int o = 32; o; o >>= 1) mx = fmaxf(mx, __shfl_xor(mx, o));
    float ex = (L < NCLSc) ? __expf(val - mx) : 0.f;
    float ssum = ex;
    for (int o = 32; o; o >>= 1) ssum += __shfl_xor(ssum, o);
    float ls = logf(ssum);
    if (L < NCLSc) out[(size_t)n * NCLSc + L] = val - mx - ls;
}

// ---------------- launch ----------------

extern "C" void kernel_launch(void* const* d_in, const int* in_sizes, int n_in,
                              void* d_out, int out_size, void* d_ws, size_t ws_size,
                              hipStream_t stream) {
    const float* x    = (const float*)d_in[0];
    const int*   ei   = (const int*)d_in[1];
    const float* W1   = (const float*)d_in[2];
    const float* as1w = (const float*)d_in[3];
    const float* ad1w = (const float*)d_in[4];
    const float* b1   = (const float*)d_in[5];
    const float* W2   = (const float*)d_in[6];
    const float* as2w = (const float*)d_in[7];
    const float* ad2w = (const float*)d_in[8];
    const float* b2   = (const float*)d_in[9];
    float* out = (float*)d_out;

    char* p = (char*)d_ws;
    __hip_bfloat16* h1    = (__hip_bfloat16*)p; p += (size_t)N_NODESc * HC1c * 2;
    __hip_bfloat16* xb    = (__hip_bfloat16*)p; p += (size_t)N_NODESc * F_INc * 2;
    __hip_bfloat16* act1b = (__hip_bfloat16*)p; p += (size_t)N_NODESc * HC1c * 2;
    __hip_bfloat16* W1T   = (__hip_bfloat16*)p; p += (size_t)HC1c * F_INc * 2;
    __hip_bfloat16* W2T   = (__hip_bfloat16*)p; p += (size_t)NCLSPc * HC1c * 2;
    float* a_s1 = (float*)p; p += (size_t)N_NODESc * 8 * 4;
    float* a_d1 = (float*)p; p += (size_t)N_NODESc * 8 * 4;
    float* h2   = (float*)p; p += (size_t)N_NODESc * NCLSc * 4;
    float* a_s2 = (float*)p; p += (size_t)N_NODESc * 4;
    float* a_d2 = (float*)p; p += (size_t)N_NODESc * 4;
    int* rowptr = (int*)p;   p += (size_t)(N_NODESc + 1) * 4;
    int* cursor = (int*)p;   p += (size_t)N_NODESc * 4;
    int* bsums  = (int*)p;   p += 256 * 4;
    int* csr    = (int*)p;   p += (size_t)E_TOTc * 4;
    (void)ws_size; (void)in_sizes; (void)n_in; (void)out_size;

    const int* src = ei;
    const int* dst = ei + N_EDGESc;

    // CSR build
    k_init_cnt<<<(N_NODESc + 255) / 256, 256, 0, stream>>>(cursor);
    k_count<<<(N_EDGESc + 255) / 256, 256, 0, stream>>>(dst, cursor);
    int nb = (N_NODESc + 511) / 512;
    k_scan1<<<nb, 512, 0, stream>>>(cursor, rowptr, bsums);
    k_scan2<<<1, 64, 0, stream>>>(bsums, nb);
    k_scan3<<<(N_NODESc + 255) / 256, 256, 0, stream>>>(rowptr, bsums, cursor);
    k_scatter<<<(E_TOTc + 255) / 256, 256, 0, stream>>>(src, dst, cursor, csr);

    // prep
    k_castx<<<(N_NODESc * F_INc / 4 + 255) / 256, 256, 0, stream>>>(x, (unsigned*)xb);
    k_prepw<<<(HC1c * F_INc + NCLSPc * HC1c + 255) / 256, 256, 0, stream>>>(W1, W2, W1T, W2T);

    // layer 1
    int nwave_blk = ((N_NODESc + 15) / 16 + 3) / 4;          // 1563
    k_gemm1<<<nwave_blk, 256, 0, stream>>>(xb, W1T, h1);
    k_alpha1<<<(N_NODESc * 8 + 255) / 256, 256, 0, stream>>>(h1, as1w, ad1w, a_s1, a_d1);
    k_agg1<<<(N_NODESc + 3) / 4, 256, 0, stream>>>(rowptr, csr, a_s1, a_d1, h1, b1, act1b);

    // layer 2
    k_gemm2<<<nwave_blk, 256, 0, stream>>>(act1b, W2T, as2w, ad2w, h2, a_s2, a_d2);
    k_agg2<<<(N_NODESc + 3) / 4, 256, 0, stream>>>(rowptr, csr, a_s2, a_d2, h2, b2, out);
}

// Round 4
// 492.425 us; speedup vs baseline: 1.8402x; 1.0881x over previous
//
#include <hip/hip_runtime.h>
#include <hip/hip_bf16.h>
#include <math.h>

#define N_NODESc 100000
#define N_EDGESc 800000
#define E_TOTc   (N_EDGESc + N_NODESc)   // 900000, includes self loops
#define F_INc    128
#define HC1c     256                      // H1*C1
#define NCLSc    40
#define NEG_SLOPEc 0.2f

typedef __attribute__((ext_vector_type(8))) short short8;   // 8 bf16 (4 VGPRs)
typedef __attribute__((ext_vector_type(4))) float f32x4;

__device__ __forceinline__ unsigned bfpack(float a, float b) {
    unsigned ua = __float_as_uint(a), ub = __float_as_uint(b);
    ua += 0x7fff + ((ua >> 16) & 1);      // RNE
    ub += 0x7fff + ((ub >> 16) & 1);
    return (ua >> 16) | (ub & 0xffff0000u);
}

// ---------------- CSR build ----------------

__global__ void k_count(const int* __restrict__ dst, int* cnt) {
    int e = blockIdx.x * blockDim.x + threadIdx.x;
    if (e < N_EDGESc) atomicAdd(&cnt[dst[e]], 1);
}

__global__ void k_scan1(const int* __restrict__ cnt, int* rowptr, int* bsums) {
    __shared__ int sh[512];
    int tid = threadIdx.x;
    int i = blockIdx.x * 512 + tid;
    int v = (i < N_NODESc) ? (cnt[i] + 1) : 0;   // +1 = self loop
    sh[tid] = v;
    __syncthreads();
    for (int off = 1; off < 512; off <<= 1) {
        int t = (tid >= off) ? sh[tid - off] : 0;
        __syncthreads();
        sh[tid] += t;
        __syncthreads();
    }
    if (i < N_NODESc) rowptr[i] = sh[tid] - v;
    if (tid == 511) bsums[blockIdx.x] = sh[511];
}

__global__ void k_scan2(int* bsums, int nb) {
    if (blockIdx.x == 0 && threadIdx.x == 0) {
        int run = 0;
        for (int b = 0; b < nb; b++) { int t = bsums[b]; bsums[b] = run; run += t; }
    }
}

__global__ void k_scan3(int* rowptr, const int* __restrict__ bsums, int* cursor,
                        int* csr) {
    int i = blockIdx.x * blockDim.x + threadIdx.x;
    if (i < N_NODESc) {
        int rp = rowptr[i] + bsums[i >> 9];
        rowptr[i] = rp;
        cursor[i] = rp + 1;      // slot rp taken by the self loop
        csr[rp] = i;
    }
    if (i == 0) rowptr[N_NODESc] = E_TOTc;
}

__global__ void k_scatter(const int* __restrict__ src, const int* __restrict__ dst,
                          int* cursor, int* csr) {
    int t = blockIdx.x * blockDim.x + threadIdx.x;
    if (t < N_EDGESc) {
        int pos = atomicAdd(&cursor[dst[t]], 1);
        csr[pos] = src[t];
    }
}

// ---------------- prep: W1^T/W2^T -> bf16 ----------------

__global__ void k_prepw(const float* __restrict__ W1, const float* __restrict__ W2,
                        __hip_bfloat16* __restrict__ W1T, __hip_bfloat16* __restrict__ W2T) {
    int i = blockIdx.x * 256 + threadIdx.x;
    if (i < HC1c * F_INc) {                                  // W1T[c][k], c<256,k<128
        int c = i >> 7, k = i & 127;
        W1T[i] = __float2bfloat16(W1[k * HC1c + c]);
    } else {
        int j = i - HC1c * F_INc;
        if (j < 48 * HC1c) {                                 // W2T[c][k], c<48,k<256
            int c = j >> 8, k = j & 255;
            W2T[j] = (c < NCLSc) ? __float2bfloat16(W2[k * NCLSc + c]) : __float2bfloat16(0.f);
        }
    }
}

// ---------------- Layer 1 GEMM (MFMA, no LDS): h1 = bf16(x) @ W1 --------------
// Fused: fp32 x load + in-register bf16 pack; epilogue computes as1/ad1 from
// the fp32 accumulators (butterfly over the 16-lane quad groups).

__global__ __launch_bounds__(256) void k_gemm1(
    const float* __restrict__ x, const __hip_bfloat16* __restrict__ W1T,
    const float* __restrict__ a_src1, const float* __restrict__ a_dst1,
    __hip_bfloat16* __restrict__ h1, float* __restrict__ as1, float* __restrict__ ad1) {
    int wave = (blockIdx.x * 256 + threadIdx.x) >> 6;
    int n0 = wave * 16;
    if (n0 >= N_NODESc) return;                 // N divisible by 16: no partial tiles
    int L = threadIdx.x & 63, lane16 = L & 15, quad = L >> 4;
    f32x4 acc[16];
    #pragma unroll
    for (int jt = 0; jt < 16; jt++) acc[jt] = (f32x4){0.f, 0.f, 0.f, 0.f};
    const float* A = x + (size_t)(n0 + lane16) * F_INc + quad * 8;
    const short* B = (const short*)W1T + lane16 * F_INc + quad * 8;
    #pragma unroll
    for (int k0 = 0; k0 < 4; k0++) {                         // K = 4 x 32
        float4 f0 = *(const float4*)(A + k0 * 32);
        float4 f1 = *(const float4*)(A + k0 * 32 + 4);
        union { short8 s; uint4 u; } af;
        af.u.x = bfpack(f0.x, f0.y); af.u.y = bfpack(f0.z, f0.w);
        af.u.z = bfpack(f1.x, f1.y); af.u.w = bfpack(f1.z, f1.w);
        #pragma unroll
        for (int jt = 0; jt < 16; jt++) {
            short8 bf = *(const short8*)(B + jt * 16 * F_INc + k0 * 32);
            acc[jt] = __builtin_amdgcn_mfma_f32_16x16x32_bf16(af.s, bf, acc[jt], 0, 0, 0);
        }
    }
    // D[row = quad*4+r][col = jt*16+lane16] -> h1 (bf16)
    #pragma unroll
    for (int jt = 0; jt < 16; jt++) {
        #pragma unroll
        for (int r = 0; r < 4; r++) {
            int n = n0 + quad * 4 + r;
            h1[(size_t)n * HC1c + jt * 16 + lane16] = __float2bfloat16(acc[jt][r]);
        }
    }
    // alpha epilogue: head h covers cols h*32..h*32+31 = jt in {2h, 2h+1}
    #pragma unroll
    for (int h = 0; h < 8; h++) {
        float ws0 = a_src1[h * 32 + lane16], ws1 = a_src1[h * 32 + 16 + lane16];
        float wd0 = a_dst1[h * 32 + lane16], wd1 = a_dst1[h * 32 + 16 + lane16];
        float ps[4], pd[4];
        #pragma unroll
        for (int r = 0; r < 4; r++) {
            ps[r] = acc[2 * h][r] * ws0 + acc[2 * h + 1][r] * ws1;
            pd[r] = acc[2 * h][r] * wd0 + acc[2 * h + 1][r] * wd1;
        }
        #pragma unroll
        for (int off = 1; off < 16; off <<= 1) {
            #pragma unroll
            for (int r = 0; r < 4; r++) {
                ps[r] += __shfl_xor(ps[r], off);
                pd[r] += __shfl_xor(pd[r], off);
            }
        }
        if (lane16 == 0) {
            #pragma unroll
            for (int r = 0; r < 4; r++) {
                int n = n0 + quad * 4 + r;
                as1[n * 8 + h] = ps[r];
                ad1[n * 8 + h] = pd[r];
            }
        }
    }
}

// ---------------- Layer 1 aggregation: wave-per-node, 2 edges/iter ------------
// Phase 1 lanes: (eL = L>>3, hL = L&7). Gather: half = L>>5 picks the edge,
// l32 = L&31 owns channels l32*8..l32*8+7 (all within head hA = l32>>2).

__global__ __launch_bounds__(256) void k_agg1(
    const int* __restrict__ rowptr, const int* __restrict__ csr,
    const float* __restrict__ as1, const float* __restrict__ ad1,
    const unsigned short* __restrict__ h1, const float* __restrict__ b1,
    unsigned short* __restrict__ act1b) {
    int n = blockIdx.x * 4 + (threadIdx.x >> 6);
    if (n >= N_NODESc) return;
    int L = threadIdx.x & 63;
    int eL = L >> 3, hL = L & 7;
    int half = L >> 5, l32 = L & 31;
    int hA = l32 >> 2;
    int beg = rowptr[n], end = rowptr[n + 1];
    float ad = ad1[n * 8 + hL];
    float m_run = -INFINITY, d_run = 0.f;
    float acc[8] = {0.f, 0.f, 0.f, 0.f, 0.f, 0.f, 0.f, 0.f};
    for (int base = beg; base < end; base += 8) {
        int m = min(8, end - base);
        int src = 0; float s = -INFINITY;
        if (eL < m) {
            src = csr[base + eL];
            float v = as1[src * 8 + hL] + ad;
            s = (v > 0.f) ? v : NEG_SLOPEc * v;
        }
        float mc = s;
        mc = fmaxf(mc, __shfl_xor(mc, 8));
        mc = fmaxf(mc, __shfl_xor(mc, 16));
        mc = fmaxf(mc, __shfl_xor(mc, 32));
        float mnew = fmaxf(m_run, mc);
        float w = (eL < m) ? __expf(s - mnew) : 0.f;
        float wsum = w;
        wsum += __shfl_xor(wsum, 8);
        wsum += __shfl_xor(wsum, 16);
        wsum += __shfl_xor(wsum, 32);
        float scale = __expf(m_run - mnew);
        d_run = d_run * scale + wsum;
        m_run = mnew;
        float sc = __shfl(scale, hA);
        #pragma unroll
        for (int j = 0; j < 8; j++) acc[j] *= sc;
        for (int ep = 0; ep < m; ep += 2) {
            int e = ep + half;
            float we = __shfl(w, e * 8 + hA);   // w==0 for e==m (odd m)
            int  se = __shfl(src, e * 8);
            if (e < m) {
                uint4 pk = *((const uint4*)(h1 + (size_t)se * HC1c) + l32);
                acc[0] += we * __uint_as_float(pk.x << 16);
                acc[1] += we * __uint_as_float(pk.x & 0xffff0000u);
                acc[2] += we * __uint_as_float(pk.y << 16);
                acc[3] += we * __uint_as_float(pk.y & 0xffff0000u);
                acc[4] += we * __uint_as_float(pk.z << 16);
                acc[5] += we * __uint_as_float(pk.z & 0xffff0000u);
                acc[6] += we * __uint_as_float(pk.w << 16);
                acc[7] += we * __uint_as_float(pk.w & 0xffff0000u);
            }
        }
    }
    float inv = 1.f / (d_run + 1e-16f);
    float inv_h = __shfl(inv, hA);
    #pragma unroll
    for (int j = 0; j < 8; j++) acc[j] += __shfl_xor(acc[j], 32);
    if (half == 0) {
        float4 b0 = ((const float4*)b1)[l32 * 2];
        float4 b4 = ((const float4*)b1)[l32 * 2 + 1];
        float o[8];
        o[0] = acc[0] * inv_h + b0.x; o[1] = acc[1] * inv_h + b0.y;
        o[2] = acc[2] * inv_h + b0.z; o[3] = acc[3] * inv_h + b0.w;
        o[4] = acc[4] * inv_h + b4.x; o[5] = acc[5] * inv_h + b4.y;
        o[6] = acc[6] * inv_h + b4.z; o[7] = acc[7] * inv_h + b4.w;
        #pragma unroll
        for (int j = 0; j < 8; j++) o[j] = (o[j] > 0.f) ? o[j] : expm1f(o[j]);
        uint4 st;
        st.x = bfpack(o[0], o[1]); st.y = bfpack(o[2], o[3]);
        st.z = bfpack(o[4], o[5]); st.w = bfpack(o[6], o[7]);
        *((uint4*)(act1b + (size_t)n * HC1c) + l32) = st;
    }
}

// ---------------- Layer 2 GEMM (MFMA) + fused alpha2; h2 out = bf16 ----------

__global__ __launch_bounds__(256) void k_gemm2(
    const unsigned short* __restrict__ act1b, const __hip_bfloat16* __restrict__ W2T,
    const float* __restrict__ a_src2, const float* __restrict__ a_dst2,
    __hip_bfloat16* __restrict__ h2b, float* __restrict__ as2, float* __restrict__ ad2) {
    int wave = (blockIdx.x * 256 + threadIdx.x) >> 6;
    int n0 = wave * 16;
    if (n0 >= N_NODESc) return;
    int L = threadIdx.x & 63, lane16 = L & 15, quad = L >> 4;
    f32x4 acc[3];
    #pragma unroll
    for (int jt = 0; jt < 3; jt++) acc[jt] = (f32x4){0.f, 0.f, 0.f, 0.f};
    const short* A = (const short*)act1b + (size_t)(n0 + lane16) * HC1c + quad * 8;
    const short* B = (const short*)W2T + lane16 * HC1c + quad * 8;
    #pragma unroll
    for (int k0 = 0; k0 < 8; k0++) {                         // K = 8 x 32
        short8 af = *(const short8*)(A + k0 * 32);
        #pragma unroll
        for (int jt = 0; jt < 3; jt++) {
            short8 bf = *(const short8*)(B + jt * 16 * HC1c + k0 * 32);
            acc[jt] = __builtin_amdgcn_mfma_f32_16x16x32_bf16(af, bf, acc[jt], 0, 0, 0);
        }
    }
    float ps[4] = {0.f, 0.f, 0.f, 0.f}, pd[4] = {0.f, 0.f, 0.f, 0.f};
    #pragma unroll
    for (int jt = 0; jt < 3; jt++) {
        int col = jt * 16 + lane16;
        float ws = (col < NCLSc) ? a_src2[col] : 0.f;
        float wd = (col < NCLSc) ? a_dst2[col] : 0.f;
        #pragma unroll
        for (int r = 0; r < 4; r++) {
            float v = acc[jt][r];
            int n = n0 + quad * 4 + r;
            if (col < NCLSc) h2b[(size_t)n * NCLSc + col] = __float2bfloat16(v);
            ps[r] += v * ws; pd[r] += v * wd;
        }
    }
    #pragma unroll
    for (int r = 0; r < 4; r++) {
        float s = ps[r], d = pd[r];
        s += __shfl_xor(s, 1); d += __shfl_xor(d, 1);
        s += __shfl_xor(s, 2); d += __shfl_xor(d, 2);
        s += __shfl_xor(s, 4); d += __shfl_xor(d, 4);
        s += __shfl_xor(s, 8); d += __shfl_xor(d, 8);
        if (lane16 == 0) {
            int n = n0 + quad * 4 + r;
            as2[n] = s; ad2[n] = d;
        }
    }
}

// ---------------- Layer 2 aggregation + bias + log_softmax: wave-per-node ----
// Lane L<20 owns classes (2L, 2L+1); bf16 h2 gather = 1 uint/lane/edge.

__global__ __launch_bounds__(256) void k_agg2(
    const int* __restrict__ rowptr, const int* __restrict__ csr,
    const float* __restrict__ as2, const float* __restrict__ ad2,
    const unsigned short* __restrict__ h2b, const float* __restrict__ b2,
    float* __restrict__ out) {
    int n = blockIdx.x * 4 + (threadIdx.x >> 6);
    if (n >= N_NODESc) return;
    int L = threadIdx.x & 63;
    int beg = rowptr[n], end = rowptr[n + 1];
    float ad = ad2[n];
    float m_run = -INFINITY, d_run = 0.f, ax = 0.f, ay = 0.f;
    for (int base = beg; base < end; base += 64) {
        int m = min(64, end - base);
        int src = 0; float s = -INFINITY;
        if (L < m) {
            src = csr[base + L];
            float v = as2[src] + ad;
            s = (v > 0.f) ? v : NEG_SLOPEc * v;
        }
        float mc = s;
        for (int o = 32; o; o >>= 1) mc = fmaxf(mc, __shfl_xor(mc, o));
        float mnew = fmaxf(m_run, mc);
        float w = (L < m) ? __expf(s - mnew) : 0.f;
        float ws = w;
        for (int o = 32; o; o >>= 1) ws += __shfl_xor(ws, o);
        float scale = __expf(m_run - mnew);
        d_run = d_run * scale + ws;
        m_run = mnew;
        ax *= scale; ay *= scale;
        for (int e = 0; e < m; e++) {
            float we = __shfl(w, e);
            int  se = __shfl(src, e);
            if (L < 20) {
                unsigned pk = *((const unsigned*)(h2b + (size_t)se * NCLSc) + L);
                ax += we * __uint_as_float(pk << 16);
                ay += we * __uint_as_float(pk & 0xffff0000u);
            }
        }
    }
    float vx = -INFINITY, vy = -INFINITY;
    if (L < 20) {
        float2 bb = ((const float2*)b2)[L];
        float inv = 1.f / (d_run + 1e-16f);
        vx = ax * inv + bb.x;
        vy = ay * inv + bb.y;
    }
    float mv = fmaxf(vx, vy);
    for (int o = 32; o; o >>= 1) mv = fmaxf(mv, __shfl_xor(mv, o));
    float ex = (L < 20) ? __expf(vx - mv) + __expf(vy - mv) : 0.f;
    for (int o = 32; o; o >>= 1) ex += __shfl_xor(ex, o);
    float ls = logf(ex);
    if (L < 20) {
        float2 o2; o2.x = vx - mv - ls; o2.y = vy - mv - ls;
        ((float2*)(out + (size_t)n * NCLSc))[L] = o2;
    }
}

// ---------------- launch ----------------

extern "C" void kernel_launch(void* const* d_in, const int* in_sizes, int n_in,
                              void* d_out, int out_size, void* d_ws, size_t ws_size,
                              hipStream_t stream) {
    const float* x    = (const float*)d_in[0];
    const int*   ei   = (const int*)d_in[1];
    const float* W1   = (const float*)d_in[2];
    const float* as1w = (const float*)d_in[3];
    const float* ad1w = (const float*)d_in[4];
    const float* b1   = (const float*)d_in[5];
    const float* W2   = (const float*)d_in[6];
    const float* as2w = (const float*)d_in[7];
    const float* ad2w = (const float*)d_in[8];
    const float* b2   = (const float*)d_in[9];
    float* out = (float*)d_out;

    char* p = (char*)d_ws;
    unsigned short* h1    = (unsigned short*)p; p += (size_t)N_NODESc * HC1c * 2;
    unsigned short* act1b = (unsigned short*)p; p += (size_t)N_NODESc * HC1c * 2;
    __hip_bfloat16* W1T   = (__hip_bfloat16*)p; p += (size_t)HC1c * F_INc * 2;
    __hip_bfloat16* W2T   = (__hip_bfloat16*)p; p += (size_t)48 * HC1c * 2;
    float* a_s1 = (float*)p; p += (size_t)N_NODESc * 8 * 4;
    float* a_d1 = (float*)p; p += (size_t)N_NODESc * 8 * 4;
    __hip_bfloat16* h2b = (__hip_bfloat16*)p; p += (size_t)N_NODESc * NCLSc * 2;
    float* a_s2 = (float*)p; p += (size_t)N_NODESc * 4;
    float* a_d2 = (float*)p; p += (size_t)N_NODESc * 4;
    int* rowptr = (int*)p;   p += (size_t)(N_NODESc + 1) * 4;
    int* cursor = (int*)p;   p += (size_t)N_NODESc * 4;
    int* bsums  = (int*)p;   p += 256 * 4;
    int* csr    = (int*)p;   p += (size_t)E_TOTc * 4;
    (void)ws_size; (void)in_sizes; (void)n_in; (void)out_size;

    const int* src = ei;
    const int* dst = ei + N_EDGESc;

    // CSR build (self loops folded into scan; cursor doubles as count buffer)
    hipMemsetAsync(cursor, 0, (size_t)N_NODESc * 4, stream);
    k_count<<<(N_EDGESc + 255) / 256, 256, 0, stream>>>(dst, cursor);
    int nb = (N_NODESc + 511) / 512;
    k_scan1<<<nb, 512, 0, stream>>>(cursor, rowptr, bsums);
    k_scan2<<<1, 64, 0, stream>>>(bsums, nb);
    k_scan3<<<(N_NODESc + 255) / 256, 256, 0, stream>>>(rowptr, bsums, cursor, csr);
    k_scatter<<<(N_EDGESc + 255) / 256, 256, 0, stream>>>(src, dst, cursor, csr);

    k_prepw<<<(HC1c * F_INc + 48 * HC1c + 255) / 256, 256, 0, stream>>>(W1, W2, W1T, W2T);

    int nwave_blk = ((N_NODESc + 15) / 16 + 3) / 4;          // 1563
    k_gemm1<<<nwave_blk, 256, 0, stream>>>(x, W1T, as1w, ad1w,
                                           (__hip_bfloat16*)h1, a_s1, a_d1);
    k_agg1<<<(N_NODESc + 3) / 4, 256, 0, stream>>>(rowptr, csr, a_s1, a_d1, h1, b1, act1b);
    k_gemm2<<<nwave_blk, 256, 0, stream>>>(act1b, W2T, as2w, ad2w, h2b, a_s2, a_d2);
    k_agg2<<<(N_NODESc + 3) / 4, 256, 0, stream>>>(rowptr, csr, a_s2, a_d2,
                                                   (const unsigned short*)h2b, b2, out);
}

// Round 6
// 486.424 us; speedup vs baseline: 1.8629x; 1.0123x over previous
//
#include <hip/hip_runtime.h>
#include <hip/hip_fp16.h>
#include <math.h>

#define N_NODESc 100000
#define N_EDGESc 800000
#define E_TOTc   (N_EDGESc + N_NODESc)   // 900000, includes self loops
#define F_INc    128
#define HC1c     256                      // H1*C1
#define NCLSc    40
#define NEG_SLOPEc 0.2f

typedef _Float16 half8 __attribute__((ext_vector_type(8)));   // MFMA A/B frag
typedef __fp16   f16x2 __attribute__((ext_vector_type(2)));   // v_pk_* / cvt_pkrtz
typedef float    f32x4 __attribute__((ext_vector_type(4)));

__device__ __forceinline__ f16x2 shfl_xor_h2(f16x2 v, int mask) {
    union { f16x2 h; int i; } u; u.h = v;
    u.i = __shfl_xor(u.i, mask);
    return u.h;
}

// ---------------- CSR build ----------------

__global__ void k_count(const int* __restrict__ dst, int* cnt) {
    int e = blockIdx.x * blockDim.x + threadIdx.x;
    if (e < N_EDGESc) atomicAdd(&cnt[dst[e]], 1);
}

__global__ void k_scan1(const int* __restrict__ cnt, int* rowptr, int* bsums) {
    __shared__ int sh[512];
    int tid = threadIdx.x;
    int i = blockIdx.x * 512 + tid;
    int v = (i < N_NODESc) ? (cnt[i] + 1) : 0;   // +1 = self loop
    sh[tid] = v;
    __syncthreads();
    for (int off = 1; off < 512; off <<= 1) {
        int t = (tid >= off) ? sh[tid - off] : 0;
        __syncthreads();
        sh[tid] += t;
        __syncthreads();
    }
    if (i < N_NODESc) rowptr[i] = sh[tid] - v;
    if (tid == 511) bsums[blockIdx.x] = sh[511];
}

__global__ void k_scan2(int* bsums, int nb) {
    if (blockIdx.x == 0 && threadIdx.x == 0) {
        int run = 0;
        for (int b = 0; b < nb; b++) { int t = bsums[b]; bsums[b] = run; run += t; }
    }
}

__global__ void k_scan3(int* rowptr, const int* __restrict__ bsums, int* cursor,
                        int* csr) {
    int i = blockIdx.x * blockDim.x + threadIdx.x;
    if (i < N_NODESc) {
        int rp = rowptr[i] + bsums[i >> 9];
        rowptr[i] = rp;
        cursor[i] = rp + 1;      // slot rp taken by the self loop
        csr[rp] = i;
    }
    if (i == 0) rowptr[N_NODESc] = E_TOTc;
}

__global__ void k_scatter(const int* __restrict__ src, const int* __restrict__ dst,
                          int* cursor, int* csr) {
    int t = blockIdx.x * blockDim.x + threadIdx.x;
    if (t < N_EDGESc) {
        int pos = atomicAdd(&cursor[dst[t]], 1);
        csr[pos] = src[t];
    }
}

// ---------------- prep: W1^T/W2^T -> fp16 ----------------

__global__ void k_prepw(const float* __restrict__ W1, const float* __restrict__ W2,
                        _Float16* __restrict__ W1T, _Float16* __restrict__ W2T) {
    int i = blockIdx.x * 256 + threadIdx.x;
    if (i < HC1c * F_INc) {                                  // W1T[c][k], c<256,k<128
        int c = i >> 7, k = i & 127;
        W1T[i] = (_Float16)W1[k * HC1c + c];
    } else {
        int j = i - HC1c * F_INc;
        if (j < 48 * HC1c) {                                 // W2T[c][k], c<48,k<256
            int c = j >> 8, k = j & 255;
            W2T[j] = (c < NCLSc) ? (_Float16)W2[k * NCLSc + c] : (_Float16)0.f;
        }
    }
}

// ---------------- Layer 1 GEMM (MFMA f16, no LDS): h1 = f16(x) @ W1 ----------
// Fused: fp32 x load + cvt_pkrtz pack; epilogue computes as1/ad1 from fp32 acc.

__global__ __launch_bounds__(256) void k_gemm1(
    const float* __restrict__ x, const _Float16* __restrict__ W1T,
    const float* __restrict__ a_src1, const float* __restrict__ a_dst1,
    _Float16* __restrict__ h1, float* __restrict__ as1, float* __restrict__ ad1) {
    int wave = (blockIdx.x * 256 + threadIdx.x) >> 6;
    int n0 = wave * 16;
    if (n0 >= N_NODESc) return;
    int L = threadIdx.x & 63, lane16 = L & 15, quad = L >> 4;
    f32x4 acc[16];
    #pragma unroll
    for (int jt = 0; jt < 16; jt++) acc[jt] = (f32x4){0.f, 0.f, 0.f, 0.f};
    const float* A = x + (size_t)(n0 + lane16) * F_INc + quad * 8;
    const _Float16* B = W1T + lane16 * F_INc + quad * 8;
    #pragma unroll
    for (int k0 = 0; k0 < 4; k0++) {                         // K = 4 x 32
        float4 f0 = *(const float4*)(A + k0 * 32);
        float4 f1 = *(const float4*)(A + k0 * 32 + 4);
        union { half8 v; f16x2 h[4]; } af;
        af.h[0] = __builtin_amdgcn_cvt_pkrtz(f0.x, f0.y);
        af.h[1] = __builtin_amdgcn_cvt_pkrtz(f0.z, f0.w);
        af.h[2] = __builtin_amdgcn_cvt_pkrtz(f1.x, f1.y);
        af.h[3] = __builtin_amdgcn_cvt_pkrtz(f1.z, f1.w);
        #pragma unroll
        for (int jt = 0; jt < 16; jt++) {
            half8 bf = *(const half8*)(B + jt * 16 * F_INc + k0 * 32);
            acc[jt] = __builtin_amdgcn_mfma_f32_16x16x32_f16(af.v, bf, acc[jt], 0, 0, 0);
        }
    }
    // D[row = quad*4+r][col = jt*16+lane16] -> h1 (fp16)
    #pragma unroll
    for (int jt = 0; jt < 16; jt++) {
        #pragma unroll
        for (int r = 0; r < 4; r++) {
            int n = n0 + quad * 4 + r;
            h1[(size_t)n * HC1c + jt * 16 + lane16] = (_Float16)acc[jt][r];
        }
    }
    // alpha epilogue: head h covers cols h*32..h*32+31 = jt in {2h, 2h+1}
    #pragma unroll
    for (int h = 0; h < 8; h++) {
        float ws0 = a_src1[h * 32 + lane16], ws1 = a_src1[h * 32 + 16 + lane16];
        float wd0 = a_dst1[h * 32 + lane16], wd1 = a_dst1[h * 32 + 16 + lane16];
        float ps[4], pd[4];
        #pragma unroll
        for (int r = 0; r < 4; r++) {
            ps[r] = acc[2 * h][r] * ws0 + acc[2 * h + 1][r] * ws1;
            pd[r] = acc[2 * h][r] * wd0 + acc[2 * h + 1][r] * wd1;
        }
        #pragma unroll
        for (int off = 1; off < 16; off <<= 1) {
            #pragma unroll
            for (int r = 0; r < 4; r++) {
                ps[r] += __shfl_xor(ps[r], off);
                pd[r] += __shfl_xor(pd[r], off);
            }
        }
        if (lane16 == 0) {
            #pragma unroll
            for (int r = 0; r < 4; r++) {
                int n = n0 + quad * 4 + r;
                as1[n * 8 + h] = ps[r];
                ad1[n * 8 + h] = pd[r];
            }
        }
    }
}

// ---------------- Layer 1 aggregation: wave-per-node, packed f16 fma ----------
// Phase 1 lanes: (eL = L>>3, hL = L&7). Gather: half = L>>5 picks the edge,
// l32 = L&31 owns channels l32*8..l32*8+7 (all within head hA = l32>>2).

__global__ __launch_bounds__(256) void k_agg1(
    const int* __restrict__ rowptr, const int* __restrict__ csr,
    const float* __restrict__ as1, const float* __restrict__ ad1,
    const _Float16* __restrict__ h1, const float* __restrict__ b1,
    _Float16* __restrict__ act1b) {
    int n = blockIdx.x * 4 + (threadIdx.x >> 6);
    if (n >= N_NODESc) return;
    int L = threadIdx.x & 63;
    int eL = L >> 3, hL = L & 7;
    int half = L >> 5, l32 = L & 31;
    int hA = l32 >> 2;
    int beg = rowptr[n], end = rowptr[n + 1];
    float ad = ad1[n * 8 + hL];
    float m_run = -INFINITY, d_run = 0.f;
    f16x2 acc4[4];
    #pragma unroll
    for (int q = 0; q < 4; q++) acc4[q] = (f16x2){(__fp16)0.f, (__fp16)0.f};
    for (int base = beg; base < end; base += 8) {
        int m = min(8, end - base);
        int src = 0; float s = -INFINITY;
        if (eL < m) {
            src = csr[base + eL];
            float v = as1[src * 8 + hL] + ad;
            s = (v > 0.f) ? v : NEG_SLOPEc * v;
        }
        float mc = s;
        mc = fmaxf(mc, __shfl_xor(mc, 8));
        mc = fmaxf(mc, __shfl_xor(mc, 16));
        mc = fmaxf(mc, __shfl_xor(mc, 32));
        float mnew = fmaxf(m_run, mc);
        float w = (eL < m) ? __expf(s - mnew) : 0.f;
        float wsum = w;
        wsum += __shfl_xor(wsum, 8);
        wsum += __shfl_xor(wsum, 16);
        wsum += __shfl_xor(wsum, 32);
        float scale = __expf(m_run - mnew);
        d_run = d_run * scale + wsum;
        m_run = mnew;
        float sc = __shfl(scale, hA);
        f16x2 sc2 = __builtin_amdgcn_cvt_pkrtz(sc, sc);
        #pragma unroll
        for (int q = 0; q < 4; q++) acc4[q] *= sc2;
        for (int ep = 0; ep < m; ep += 2) {
            int e = ep + half;
            float we = __shfl(w, e * 8 + hA);
            int  se = __shfl(src, e * 8);
            if (e < m) {
                f16x2 we2 = __builtin_amdgcn_cvt_pkrtz(we, we);
                union { uint4 u; f16x2 h[4]; } pk;
                pk.u = *((const uint4*)(h1 + (size_t)se * HC1c) + l32);
                acc4[0] += we2 * pk.h[0];
                acc4[1] += we2 * pk.h[1];
                acc4[2] += we2 * pk.h[2];
                acc4[3] += we2 * pk.h[3];
            }
        }
    }
    float inv = 1.f / (d_run + 1e-16f);
    float inv_h = __shfl(inv, hA);
    #pragma unroll
    for (int q = 0; q < 4; q++) acc4[q] += shfl_xor_h2(acc4[q], 32);
    if (half == 0) {
        float4 b0 = ((const float4*)b1)[l32 * 2];
        float4 b4 = ((const float4*)b1)[l32 * 2 + 1];
        float o[8];
        o[0] = (float)acc4[0][0] * inv_h + b0.x; o[1] = (float)acc4[0][1] * inv_h + b0.y;
        o[2] = (float)acc4[1][0] * inv_h + b0.z; o[3] = (float)acc4[1][1] * inv_h + b0.w;
        o[4] = (float)acc4[2][0] * inv_h + b4.x; o[5] = (float)acc4[2][1] * inv_h + b4.y;
        o[6] = (float)acc4[3][0] * inv_h + b4.z; o[7] = (float)acc4[3][1] * inv_h + b4.w;
        #pragma unroll
        for (int j = 0; j < 8; j++) o[j] = (o[j] > 0.f) ? o[j] : expm1f(o[j]);
        union { uint4 u; f16x2 h[4]; } st;
        st.h[0] = __builtin_amdgcn_cvt_pkrtz(o[0], o[1]);
        st.h[1] = __builtin_amdgcn_cvt_pkrtz(o[2], o[3]);
        st.h[2] = __builtin_amdgcn_cvt_pkrtz(o[4], o[5]);
        st.h[3] = __builtin_amdgcn_cvt_pkrtz(o[6], o[7]);
        *((uint4*)(act1b + (size_t)n * HC1c) + l32) = st.u;
    }
}

// ---------------- Layer 2 GEMM (MFMA f16) + fused alpha2; h2 out = fp16 ------

__global__ __launch_bounds__(256) void k_gemm2(
    const _Float16* __restrict__ act1b, const _Float16* __restrict__ W2T,
    const float* __restrict__ a_src2, const float* __restrict__ a_dst2,
    _Float16* __restrict__ h2b, float* __restrict__ as2, float* __restrict__ ad2) {
    int wave = (blockIdx.x * 256 + threadIdx.x) >> 6;
    int n0 = wave * 16;
    if (n0 >= N_NODESc) return;
    int L = threadIdx.x & 63, lane16 = L & 15, quad = L >> 4;
    f32x4 acc[3];
    #pragma unroll
    for (int jt = 0; jt < 3; jt++) acc[jt] = (f32x4){0.f, 0.f, 0.f, 0.f};
    const _Float16* A = act1b + (size_t)(n0 + lane16) * HC1c + quad * 8;
    const _Float16* B = W2T + lane16 * HC1c + quad * 8;
    #pragma unroll
    for (int k0 = 0; k0 < 8; k0++) {                         // K = 8 x 32
        half8 af = *(const half8*)(A + k0 * 32);
        #pragma unroll
        for (int jt = 0; jt < 3; jt++) {
            half8 bf = *(const half8*)(B + jt * 16 * HC1c + k0 * 32);
            acc[jt] = __builtin_amdgcn_mfma_f32_16x16x32_f16(af, bf, acc[jt], 0, 0, 0);
        }
    }
    float ps[4] = {0.f, 0.f, 0.f, 0.f}, pd[4] = {0.f, 0.f, 0.f, 0.f};
    #pragma unroll
    for (int jt = 0; jt < 3; jt++) {
        int col = jt * 16 + lane16;
        float ws = (col < NCLSc) ? a_src2[col] : 0.f;
        float wd = (col < NCLSc) ? a_dst2[col] : 0.f;
        #pragma unroll
        for (int r = 0; r < 4; r++) {
            float v = acc[jt][r];
            int n = n0 + quad * 4 + r;
            if (col < NCLSc) h2b[(size_t)n * NCLSc + col] = (_Float16)v;
            ps[r] += v * ws; pd[r] += v * wd;
        }
    }
    #pragma unroll
    for (int r = 0; r < 4; r++) {
        float s = ps[r], d = pd[r];
        s += __shfl_xor(s, 1); d += __shfl_xor(d, 1);
        s += __shfl_xor(s, 2); d += __shfl_xor(d, 2);
        s += __shfl_xor(s, 4); d += __shfl_xor(d, 4);
        s += __shfl_xor(s, 8); d += __shfl_xor(d, 8);
        if (lane16 == 0) {
            int n = n0 + quad * 4 + r;
            as2[n] = s; ad2[n] = d;
        }
    }
}

// ---------------- Layer 2 aggregation + bias + log_softmax: wave-per-node ----
// Lane L<20 owns classes (2L, 2L+1); fp16 h2 gather = 1 half2/lane/edge.

__global__ __launch_bounds__(256) void k_agg2(
    const int* __restrict__ rowptr, const int* __restrict__ csr,
    const float* __restrict__ as2, const float* __restrict__ ad2,
    const _Float16* __restrict__ h2b, const float* __restrict__ b2,
    float* __restrict__ out) {
    int n = blockIdx.x * 4 + (threadIdx.x >> 6);
    if (n >= N_NODESc) return;
    int L = threadIdx.x & 63;
    int beg = rowptr[n], end = rowptr[n + 1];
    float ad = ad2[n];
    float m_run = -INFINITY, d_run = 0.f;
    f16x2 acc2 = (f16x2){(__fp16)0.f, (__fp16)0.f};
    for (int base = beg; base < end; base += 64) {
        int m = min(64, end - base);
        int src = 0; float s = -INFINITY;
        if (L < m) {
            src = csr[base + L];
            float v = as2[src] + ad;
            s = (v > 0.f) ? v : NEG_SLOPEc * v;
        }
        float mc = s;
        for (int o = 32; o; o >>= 1) mc = fmaxf(mc, __shfl_xor(mc, o));
        float mnew = fmaxf(m_run, mc);
        float w = (L < m) ? __expf(s - mnew) : 0.f;
        float ws = w;
        for (int o = 32; o; o >>= 1) ws += __shfl_xor(ws, o);
        float scale = __expf(m_run - mnew);
        d_run = d_run * scale + ws;
        m_run = mnew;
        f16x2 sc2 = __builtin_amdgcn_cvt_pkrtz(scale, scale);
        acc2 *= sc2;
        for (int e = 0; e < m; e++) {
            float we = __shfl(w, e);
            int  se = __shfl(src, e);
            if (L < 20) {
                f16x2 we2 = __builtin_amdgcn_cvt_pkrtz(we, we);
                union { unsigned u; f16x2 h; } pk;
                pk.u = *((const unsigned*)(h2b + (size_t)se * NCLSc) + L);
                acc2 += we2 * pk.h;
            }
        }
    }
    float vx = -INFINITY, vy = -INFINITY;
    if (L < 20) {
        float2 bb = ((const float2*)b2)[L];
        float inv = 1.f / (d_run + 1e-16f);
        vx = (float)acc2[0] * inv + bb.x;
        vy = (float)acc2[1] * inv + bb.y;
    }
    float mv = fmaxf(vx, vy);
    for (int o = 32; o; o >>= 1) mv = fmaxf(mv, __shfl_xor(mv, o));
    float ex = (L < 20) ? __expf(vx - mv) + __expf(vy - mv) : 0.f;
    for (int o = 32; o; o >>= 1) ex += __shfl_xor(ex, o);
    float ls = logf(ex);
    if (L < 20) {
        float2 o2; o2.x = vx - mv - ls; o2.y = vy - mv - ls;
        ((float2*)(out + (size_t)n * NCLSc))[L] = o2;
    }
}

// ---------------- launch ----------------

extern "C" void kernel_launch(void* const* d_in, const int* in_sizes, int n_in,
                              void* d_out, int out_size, void* d_ws, size_t ws_size,
                              hipStream_t stream) {
    const float* x    = (const float*)d_in[0];
    const int*   ei   = (const int*)d_in[1];
    const float* W1   = (const float*)d_in[2];
    const float* as1w = (const float*)d_in[3];
    const float* ad1w = (const float*)d_in[4];
    const float* b1   = (const float*)d_in[5];
    const float* W2   = (const float*)d_in[6];
    const float* as2w = (const float*)d_in[7];
    const float* ad2w = (const float*)d_in[8];
    const float* b2   = (const float*)d_in[9];
    float* out = (float*)d_out;

    char* p = (char*)d_ws;
    _Float16* h1    = (_Float16*)p; p += (size_t)N_NODESc * HC1c * 2;
    _Float16* act1b = (_Float16*)p; p += (size_t)N_NODESc * HC1c * 2;
    _Float16* W1T   = (_Float16*)p; p += (size_t)HC1c * F_INc * 2;
    _Float16* W2T   = (_Float16*)p; p += (size_t)48 * HC1c * 2;
    float* a_s1 = (float*)p; p += (size_t)N_NODESc * 8 * 4;
    float* a_d1 = (float*)p; p += (size_t)N_NODESc * 8 * 4;
    _Float16* h2b = (_Float16*)p; p += (size_t)N_NODESc * NCLSc * 2;
    float* a_s2 = (float*)p; p += (size_t)N_NODESc * 4;
    float* a_d2 = (float*)p; p += (size_t)N_NODESc * 4;
    int* rowptr = (int*)p;   p += (size_t)(N_NODESc + 1) * 4;
    int* cursor = (int*)p;   p += (size_t)N_NODESc * 4;
    int* bsums  = (int*)p;   p += 256 * 4;
    int* csr    = (int*)p;   p += (size_t)E_TOTc * 4;
    (void)ws_size; (void)in_sizes; (void)n_in; (void)out_size;

    const int* src = ei;
    const int* dst = ei + N_EDGESc;

    // CSR build (self loops folded into scan; cursor doubles as count buffer)
    (void)hipMemsetAsync(cursor, 0, (size_t)N_NODESc * 4, stream);
    k_count<<<(N_EDGESc + 255) / 256, 256, 0, stream>>>(dst, cursor);
    int nb = (N_NODESc + 511) / 512;
    k_scan1<<<nb, 512, 0, stream>>>(cursor, rowptr, bsums);
    k_scan2<<<1, 64, 0, stream>>>(bsums, nb);
    k_scan3<<<(N_NODESc + 255) / 256, 256, 0, stream>>>(rowptr, bsums, cursor, csr);
    k_scatter<<<(N_EDGESc + 255) / 256, 256, 0, stream>>>(src, dst, cursor, csr);

    k_prepw<<<(HC1c * F_INc + 48 * HC1c + 255) / 256, 256, 0, stream>>>(W1, W2, W1T, W2T);

    int nwave_blk = ((N_NODESc + 15) / 16 + 3) / 4;          // 1563
    k_gemm1<<<nwave_blk, 256, 0, stream>>>(x, W1T, as1w, ad1w, h1, a_s1, a_d1);
    k_agg1<<<(N_NODESc + 3) / 4, 256, 0, stream>>>(rowptr, csr, a_s1, a_d1, h1, b1, act1b);
    k_gemm2<<<nwave_blk, 256, 0, stream>>>(act1b, W2T, as2w, ad2w, h2b, a_s2, a_d2);
    k_agg2<<<(N_NODESc + 3) / 4, 256, 0, stream>>>(rowptr, csr, a_s2, a_d2, h2b, b2, out);
}

// Round 7
// 431.389 us; speedup vs baseline: 2.1006x; 1.1276x over previous
//
#include <hip/hip_runtime.h>
#include <hip/hip_fp16.h>
#include <math.h>

#define N_NODESc 100000
#define N_EDGESc 800000
#define E_TOTc   (N_EDGESc + N_NODESc)   // 900000, includes self loops
#define F_INc    128
#define HC1c     256                      // H1*C1
#define NCLSc    40
#define NEG_SLOPEc 0.2f

typedef _Float16 half8 __attribute__((ext_vector_type(8)));   // MFMA A/B frag
typedef __fp16   f16x2 __attribute__((ext_vector_type(2)));   // v_pk_* / cvt_pkrtz
typedef float    f32x4 __attribute__((ext_vector_type(4)));

__device__ __forceinline__ f16x2 shfl_xor_h2(f16x2 v, int mask) {
    union { f16x2 h; int i; } u; u.h = v;
    u.i = __shfl_xor(u.i, mask);
    return u.h;
}

// ---------------- CSR build ----------------

__global__ void k_count(const int* __restrict__ dst, int* cnt) {
    int e = blockIdx.x * blockDim.x + threadIdx.x;
    if (e < N_EDGESc) atomicAdd(&cnt[dst[e]], 1);
}

__global__ void k_scan1(const int* __restrict__ cnt, int* rowptr, int* bsums) {
    __shared__ int sh[512];
    int tid = threadIdx.x;
    int i = blockIdx.x * 512 + tid;
    int v = (i < N_NODESc) ? (cnt[i] + 1) : 0;   // +1 = self loop
    sh[tid] = v;
    __syncthreads();
    for (int off = 1; off < 512; off <<= 1) {
        int t = (tid >= off) ? sh[tid - off] : 0;
        __syncthreads();
        sh[tid] += t;
        __syncthreads();
    }
    if (i < N_NODESc) rowptr[i] = sh[tid] - v;
    if (tid == 511) bsums[blockIdx.x] = sh[511];
}

// one wave, shuffle prefix scan over nb (<=512) block sums
__global__ void k_scan2(int* bsums, int nb) {
    int L = threadIdx.x;          // 64 threads
    int run = 0;
    for (int s = 0; s < nb; s += 64) {
        int idx = s + L;
        int o = (idx < nb) ? bsums[idx] : 0;
        int v = o;
        #pragma unroll
        for (int off = 1; off < 64; off <<= 1) {
            int t = __shfl_up(v, off);
            if (L >= off) v += t;
        }
        int total = __shfl(v, 63);
        if (idx < nb) bsums[idx] = run + v - o;   // exclusive
        run += total;
    }
}

__global__ void k_scan3(int* rowptr, const int* __restrict__ bsums, int* cursor,
                        int* csr) {
    int i = blockIdx.x * blockDim.x + threadIdx.x;
    if (i < N_NODESc) {
        int rp = rowptr[i] + bsums[i >> 9];
        rowptr[i] = rp;
        cursor[i] = rp + 1;      // slot rp taken by the self loop
        csr[rp] = i;
    }
    if (i == 0) rowptr[N_NODESc] = E_TOTc;
}

__global__ void k_scatter(const int* __restrict__ src, const int* __restrict__ dst,
                          int* cursor, int* csr) {
    int t = blockIdx.x * blockDim.x + threadIdx.x;
    if (t < N_EDGESc) {
        int pos = atomicAdd(&cursor[dst[t]], 1);
        csr[pos] = src[t];
    }
}

// ---------------- prep: W1^T/W2^T -> fp16 ----------------

__global__ void k_prepw(const float* __restrict__ W1, const float* __restrict__ W2,
                        _Float16* __restrict__ W1T, _Float16* __restrict__ W2T) {
    int i = blockIdx.x * 256 + threadIdx.x;
    if (i < HC1c * F_INc) {                                  // W1T[c][k], c<256,k<128
        int c = i >> 7, k = i & 127;
        W1T[i] = (_Float16)W1[k * HC1c + c];
    } else {
        int j = i - HC1c * F_INc;
        if (j < 48 * HC1c) {                                 // W2T[c][k], c<48,k<256
            int c = j >> 8, k = j & 255;
            W2T[j] = (c < NCLSc) ? (_Float16)W2[k * NCLSc + c] : (_Float16)0.f;
        }
    }
}

// ---------------- Layer 1 GEMM (MFMA f16, no LDS): h1 = f16(x) @ W1 ----------

__global__ __launch_bounds__(256) void k_gemm1(
    const float* __restrict__ x, const _Float16* __restrict__ W1T,
    const float* __restrict__ a_src1, const float* __restrict__ a_dst1,
    _Float16* __restrict__ h1, float* __restrict__ as1, float* __restrict__ ad1) {
    int wave = (blockIdx.x * 256 + threadIdx.x) >> 6;
    int n0 = wave * 16;
    if (n0 >= N_NODESc) return;
    int L = threadIdx.x & 63, lane16 = L & 15, quad = L >> 4;
    f32x4 acc[16];
    #pragma unroll
    for (int jt = 0; jt < 16; jt++) acc[jt] = (f32x4){0.f, 0.f, 0.f, 0.f};
    const float* A = x + (size_t)(n0 + lane16) * F_INc + quad * 8;
    const _Float16* B = W1T + lane16 * F_INc + quad * 8;
    #pragma unroll
    for (int k0 = 0; k0 < 4; k0++) {                         // K = 4 x 32
        float4 f0 = *(const float4*)(A + k0 * 32);
        float4 f1 = *(const float4*)(A + k0 * 32 + 4);
        union { half8 v; f16x2 h[4]; } af;
        af.h[0] = __builtin_amdgcn_cvt_pkrtz(f0.x, f0.y);
        af.h[1] = __builtin_amdgcn_cvt_pkrtz(f0.z, f0.w);
        af.h[2] = __builtin_amdgcn_cvt_pkrtz(f1.x, f1.y);
        af.h[3] = __builtin_amdgcn_cvt_pkrtz(f1.z, f1.w);
        #pragma unroll
        for (int jt = 0; jt < 16; jt++) {
            half8 bf = *(const half8*)(B + jt * 16 * F_INc + k0 * 32);
            acc[jt] = __builtin_amdgcn_mfma_f32_16x16x32_f16(af.v, bf, acc[jt], 0, 0, 0);
        }
    }
    #pragma unroll
    for (int jt = 0; jt < 16; jt++) {
        #pragma unroll
        for (int r = 0; r < 4; r++) {
            int n = n0 + quad * 4 + r;
            h1[(size_t)n * HC1c + jt * 16 + lane16] = (_Float16)acc[jt][r];
        }
    }
    #pragma unroll
    for (int h = 0; h < 8; h++) {
        float ws0 = a_src1[h * 32 + lane16], ws1 = a_src1[h * 32 + 16 + lane16];
        float wd0 = a_dst1[h * 32 + lane16], wd1 = a_dst1[h * 32 + 16 + lane16];
        float ps[4], pd[4];
        #pragma unroll
        for (int r = 0; r < 4; r++) {
            ps[r] = acc[2 * h][r] * ws0 + acc[2 * h + 1][r] * ws1;
            pd[r] = acc[2 * h][r] * wd0 + acc[2 * h + 1][r] * wd1;
        }
        #pragma unroll
        for (int off = 1; off < 16; off <<= 1) {
            #pragma unroll
            for (int r = 0; r < 4; r++) {
                ps[r] += __shfl_xor(ps[r], off);
                pd[r] += __shfl_xor(pd[r], off);
            }
        }
        if (lane16 == 0) {
            #pragma unroll
            for (int r = 0; r < 4; r++) {
                int n = n0 + quad * 4 + r;
                as1[n * 8 + h] = ps[r];
                ad1[n * 8 + h] = pd[r];
            }
        }
    }
}

// ---------------- Layer 1 aggregation: wave-per-node, CHUNK=16, batched MLP ---
// Phase 1: lane (eL=L>>3, hL=L&7) scores edges eL and eL+8 for head hL.
// Gather: half = L>>5 picks edge within a pair, l32 = L&31 owns 8 channels,
// head hA = l32>>2. Loads batched 4-at-a-time (zero-init + predicated).

__global__ __launch_bounds__(256) void k_agg1(
    const int* __restrict__ rowptr, const int* __restrict__ csr,
    const float* __restrict__ as1, const float* __restrict__ ad1,
    const _Float16* __restrict__ h1, const float* __restrict__ b1,
    _Float16* __restrict__ act1b) {
    int n = blockIdx.x * 4 + (threadIdx.x >> 6);
    if (n >= N_NODESc) return;
    int L = threadIdx.x & 63;
    int eL = L >> 3, hL = L & 7;
    int half = L >> 5, l32 = L & 31;
    int hA = l32 >> 2;
    int beg = rowptr[n], end = rowptr[n + 1];
    float ad = ad1[n * 8 + hL];
    float m_run = -INFINITY, d_run = 0.f;
    f16x2 acc4[4];
    #pragma unroll
    for (int q = 0; q < 4; q++) acc4[q] = (f16x2){(__fp16)0.f, (__fp16)0.f};
    for (int base = beg; base < end; base += 16) {
        int m = min(16, end - base);
        int src0 = 0, src1 = 0;
        float s0 = -INFINITY, s1 = -INFINITY;
        if (eL < m) {
            src0 = csr[base + eL];
            float v = as1[src0 * 8 + hL] + ad;
            s0 = (v > 0.f) ? v : NEG_SLOPEc * v;
        }
        if (eL + 8 < m) {
            src1 = csr[base + eL + 8];
            float v = as1[src1 * 8 + hL] + ad;
            s1 = (v > 0.f) ? v : NEG_SLOPEc * v;
        }
        float mc = fmaxf(s0, s1);
        mc = fmaxf(mc, __shfl_xor(mc, 8));
        mc = fmaxf(mc, __shfl_xor(mc, 16));
        mc = fmaxf(mc, __shfl_xor(mc, 32));
        float mnew = fmaxf(m_run, mc);
        float w0 = (eL < m) ? __expf(s0 - mnew) : 0.f;
        float w1 = (eL + 8 < m) ? __expf(s1 - mnew) : 0.f;
        float wsum = w0 + w1;
        wsum += __shfl_xor(wsum, 8);
        wsum += __shfl_xor(wsum, 16);
        wsum += __shfl_xor(wsum, 32);
        float scale = __expf(m_run - mnew);
        d_run = d_run * scale + wsum;
        m_run = mnew;
        float sc = __shfl(scale, hA);
        f16x2 sc2 = __builtin_amdgcn_cvt_pkrtz(sc, sc);
        #pragma unroll
        for (int q = 0; q < 4; q++) acc4[q] *= sc2;
        // group A: edges 0..7
        {
            float we[4]; int se[4]; uint4 pk[4];
            #pragma unroll
            for (int j = 0; j < 4; j++) {
                int e = 2 * j + half;
                we[j] = __shfl(w0, e * 8 + hA);
                se[j] = __shfl(src0, e * 8 + hA);
            }
            #pragma unroll
            for (int j = 0; j < 4; j++) {
                int e = 2 * j + half;
                pk[j] = (uint4){0u, 0u, 0u, 0u};
                if (e < m) pk[j] = *((const uint4*)(h1 + (size_t)se[j] * HC1c) + l32);
            }
            #pragma unroll
            for (int j = 0; j < 4; j++) {
                f16x2 we2 = __builtin_amdgcn_cvt_pkrtz(we[j], we[j]);
                union { uint4 u; f16x2 h[4]; } pp; pp.u = pk[j];
                acc4[0] += we2 * pp.h[0];
                acc4[1] += we2 * pp.h[1];
                acc4[2] += we2 * pp.h[2];
                acc4[3] += we2 * pp.h[3];
            }
        }
        // group B: edges 8..15 (wave-uniform skip)
        if (m > 8) {
            float we[4]; int se[4]; uint4 pk[4];
            #pragma unroll
            for (int j = 0; j < 4; j++) {
                int el = 2 * j + half;
                we[j] = __shfl(w1, el * 8 + hA);
                se[j] = __shfl(src1, el * 8 + hA);
            }
            #pragma unroll
            for (int j = 0; j < 4; j++) {
                int e = 8 + 2 * j + half;
                pk[j] = (uint4){0u, 0u, 0u, 0u};
                if (e < m) pk[j] = *((const uint4*)(h1 + (size_t)se[j] * HC1c) + l32);
            }
            #pragma unroll
            for (int j = 0; j < 4; j++) {
                f16x2 we2 = __builtin_amdgcn_cvt_pkrtz(we[j], we[j]);
                union { uint4 u; f16x2 h[4]; } pp; pp.u = pk[j];
                acc4[0] += we2 * pp.h[0];
                acc4[1] += we2 * pp.h[1];
                acc4[2] += we2 * pp.h[2];
                acc4[3] += we2 * pp.h[3];
            }
        }
    }
    float inv = 1.f / (d_run + 1e-16f);
    float inv_h = __shfl(inv, hA);
    #pragma unroll
    for (int q = 0; q < 4; q++) acc4[q] += shfl_xor_h2(acc4[q], 32);
    if (half == 0) {
        float4 b0 = ((const float4*)b1)[l32 * 2];
        float4 b4 = ((const float4*)b1)[l32 * 2 + 1];
        float o[8];
        o[0] = (float)acc4[0][0] * inv_h + b0.x; o[1] = (float)acc4[0][1] * inv_h + b0.y;
        o[2] = (float)acc4[1][0] * inv_h + b0.z; o[3] = (float)acc4[1][1] * inv_h + b0.w;
        o[4] = (float)acc4[2][0] * inv_h + b4.x; o[5] = (float)acc4[2][1] * inv_h + b4.y;
        o[6] = (float)acc4[3][0] * inv_h + b4.z; o[7] = (float)acc4[3][1] * inv_h + b4.w;
        #pragma unroll
        for (int j = 0; j < 8; j++) o[j] = (o[j] > 0.f) ? o[j] : expm1f(o[j]);
        union { uint4 u; f16x2 h[4]; } st;
        st.h[0] = __builtin_amdgcn_cvt_pkrtz(o[0], o[1]);
        st.h[1] = __builtin_amdgcn_cvt_pkrtz(o[2], o[3]);
        st.h[2] = __builtin_amdgcn_cvt_pkrtz(o[4], o[5]);
        st.h[3] = __builtin_amdgcn_cvt_pkrtz(o[6], o[7]);
        *((uint4*)(act1b + (size_t)n * HC1c) + l32) = st.u;
    }
}

// ---------------- Layer 2 GEMM (MFMA f16) + fused alpha2; h2 out = fp16 ------

__global__ __launch_bounds__(256) void k_gemm2(
    const _Float16* __restrict__ act1b, const _Float16* __restrict__ W2T,
    const float* __restrict__ a_src2, const float* __restrict__ a_dst2,
    _Float16* __restrict__ h2b, float* __restrict__ as2, float* __restrict__ ad2) {
    int wave = (blockIdx.x * 256 + threadIdx.x) >> 6;
    int n0 = wave * 16;
    if (n0 >= N_NODESc) return;
    int L = threadIdx.x & 63, lane16 = L & 15, quad = L >> 4;
    f32x4 acc[3];
    #pragma unroll
    for (int jt = 0; jt < 3; jt++) acc[jt] = (f32x4){0.f, 0.f, 0.f, 0.f};
    const _Float16* A = act1b + (size_t)(n0 + lane16) * HC1c + quad * 8;
    const _Float16* B = W2T + lane16 * HC1c + quad * 8;
    #pragma unroll
    for (int k0 = 0; k0 < 8; k0++) {                         // K = 8 x 32
        half8 af = *(const half8*)(A + k0 * 32);
        #pragma unroll
        for (int jt = 0; jt < 3; jt++) {
            half8 bf = *(const half8*)(B + jt * 16 * HC1c + k0 * 32);
            acc[jt] = __builtin_amdgcn_mfma_f32_16x16x32_f16(af, bf, acc[jt], 0, 0, 0);
        }
    }
    float ps[4] = {0.f, 0.f, 0.f, 0.f}, pd[4] = {0.f, 0.f, 0.f, 0.f};
    #pragma unroll
    for (int jt = 0; jt < 3; jt++) {
        int col = jt * 16 + lane16;
        float ws = (col < NCLSc) ? a_src2[col] : 0.f;
        float wd = (col < NCLSc) ? a_dst2[col] : 0.f;
        #pragma unroll
        for (int r = 0; r < 4; r++) {
            float v = acc[jt][r];
            int n = n0 + quad * 4 + r;
            if (col < NCLSc) h2b[(size_t)n * NCLSc + col] = (_Float16)v;
            ps[r] += v * ws; pd[r] += v * wd;
        }
    }
    #pragma unroll
    for (int r = 0; r < 4; r++) {
        float s = ps[r], d = pd[r];
        s += __shfl_xor(s, 1); d += __shfl_xor(d, 1);
        s += __shfl_xor(s, 2); d += __shfl_xor(d, 2);
        s += __shfl_xor(s, 4); d += __shfl_xor(d, 4);
        s += __shfl_xor(s, 8); d += __shfl_xor(d, 8);
        if (lane16 == 0) {
            int n = n0 + quad * 4 + r;
            as2[n] = s; ad2[n] = d;
        }
    }
}

// ---------------- Layer 2 aggregation + bias + log_softmax: wave-per-node ----
// Gather: lane group g=L/20 handles edge 3j+g, cls=L%20 owns classes (2cls,2cls+1).

__global__ __launch_bounds__(256) void k_agg2(
    const int* __restrict__ rowptr, const int* __restrict__ csr,
    const float* __restrict__ as2, const float* __restrict__ ad2,
    const _Float16* __restrict__ h2b, const float* __restrict__ b2,
    float* __restrict__ out) {
    int n = blockIdx.x * 4 + (threadIdx.x >> 6);
    if (n >= N_NODESc) return;
    int L = threadIdx.x & 63;
    int g = L / 20, cls = L % 20;        // g==3 for lanes 60..63 (gather-idle)
    int beg = rowptr[n], end = rowptr[n + 1];
    float ad = ad2[n];
    float m_run = -INFINITY, d_run = 0.f;
    f16x2 acc2 = (f16x2){(__fp16)0.f, (__fp16)0.f};
    for (int base = beg; base < end; base += 64) {
        int m = min(64, end - base);
        int src = 0; float s = -INFINITY;
        if (L < m) {
            src = csr[base + L];
            float v = as2[src] + ad;
            s = (v > 0.f) ? v : NEG_SLOPEc * v;
        }
        float mc = s;
        for (int o = 32; o; o >>= 1) mc = fmaxf(mc, __shfl_xor(mc, o));
        float mnew = fmaxf(m_run, mc);
        float w = (L < m) ? __expf(s - mnew) : 0.f;
        float ws = w;
        for (int o = 32; o; o >>= 1) ws += __shfl_xor(ws, o);
        float scale = __expf(m_run - mnew);
        d_run = d_run * scale + ws;
        m_run = mnew;
        f16x2 sc2 = __builtin_amdgcn_cvt_pkrtz(scale, scale);
        acc2 *= sc2;
        for (int j = 0; j < m; j += 3) {
            int e = j + g;
            int lane = (e < 64) ? e : 63;
            float we = __shfl(w, lane);
            int  se = __shfl(src, lane);
            if (g < 3 && e < m) {
                f16x2 we2 = __builtin_amdgcn_cvt_pkrtz(we, we);
                union { unsigned u; f16x2 h; } pk;
                pk.u = *((const unsigned*)(h2b + (size_t)se * NCLSc) + cls);
                acc2 += we2 * pk.h;
            }
        }
    }
    // combine the 3 gather groups onto lanes 0..19
    union { f16x2 h; int i; } au; au.h = acc2;
    int i1 = __shfl(au.i, (L + 20) & 63);
    int i2 = __shfl(au.i, (L + 40) & 63);
    union { int i; f16x2 h; } b1u, b2u; b1u.i = i1; b2u.i = i2;
    acc2 = acc2 + b1u.h + b2u.h;
    float vx = -INFINITY, vy = -INFINITY;
    if (L < 20) {
        float2 bb = ((const float2*)b2)[L];
        float inv = 1.f / (d_run + 1e-16f);
        vx = (float)acc2[0] * inv + bb.x;
        vy = (float)acc2[1] * inv + bb.y;
    }
    float mv = fmaxf(vx, vy);
    for (int o = 32; o; o >>= 1) mv = fmaxf(mv, __shfl_xor(mv, o));
    float ex = (L < 20) ? __expf(vx - mv) + __expf(vy - mv) : 0.f;
    for (int o = 32; o; o >>= 1) ex += __shfl_xor(ex, o);
    float ls = logf(ex);
    if (L < 20) {
        float2 o2; o2.x = vx - mv - ls; o2.y = vy - mv - ls;
        ((float2*)(out + (size_t)n * NCLSc))[L] = o2;
    }
}

// ---------------- launch ----------------

extern "C" void kernel_launch(void* const* d_in, const int* in_sizes, int n_in,
                              void* d_out, int out_size, void* d_ws, size_t ws_size,
                              hipStream_t stream) {
    const float* x    = (const float*)d_in[0];
    const int*   ei   = (const int*)d_in[1];
    const float* W1   = (const float*)d_in[2];
    const float* as1w = (const float*)d_in[3];
    const float* ad1w = (const float*)d_in[4];
    const float* b1   = (const float*)d_in[5];
    const float* W2   = (const float*)d_in[6];
    const float* as2w = (const float*)d_in[7];
    const float* ad2w = (const float*)d_in[8];
    const float* b2   = (const float*)d_in[9];
    float* out = (float*)d_out;

    char* p = (char*)d_ws;
    _Float16* h1    = (_Float16*)p; p += (size_t)N_NODESc * HC1c * 2;
    _Float16* act1b = (_Float16*)p; p += (size_t)N_NODESc * HC1c * 2;
    _Float16* W1T   = (_Float16*)p; p += (size_t)HC1c * F_INc * 2;
    _Float16* W2T   = (_Float16*)p; p += (size_t)48 * HC1c * 2;
    float* a_s1 = (float*)p; p += (size_t)N_NODESc * 8 * 4;
    float* a_d1 = (float*)p; p += (size_t)N_NODESc * 8 * 4;
    _Float16* h2b = (_Float16*)p; p += (size_t)N_NODESc * NCLSc * 2;
    float* a_s2 = (float*)p; p += (size_t)N_NODESc * 4;
    float* a_d2 = (float*)p; p += (size_t)N_NODESc * 4;
    int* rowptr = (int*)p;   p += (size_t)(N_NODESc + 1) * 4;
    int* cursor = (int*)p;   p += (size_t)N_NODESc * 4;
    int* bsums  = (int*)p;   p += 512 * 4;
    int* csr    = (int*)p;   p += (size_t)E_TOTc * 4;
    (void)ws_size; (void)in_sizes; (void)n_in; (void)out_size;

    const int* src = ei;
    const int* dst = ei + N_EDGESc;

    // CSR build (self loops folded into scan; cursor doubles as count buffer)
    (void)hipMemsetAsync(cursor, 0, (size_t)N_NODESc * 4, stream);
    k_count<<<(N_EDGESc + 255) / 256, 256, 0, stream>>>(dst, cursor);
    int nb = (N_NODESc + 511) / 512;
    k_scan1<<<nb, 512, 0, stream>>>(cursor, rowptr, bsums);
    k_scan2<<<1, 64, 0, stream>>>(bsums, nb);
    k_scan3<<<(N_NODESc + 255) / 256, 256, 0, stream>>>(rowptr, bsums, cursor, csr);
    k_scatter<<<(N_EDGESc + 255) / 256, 256, 0, stream>>>(src, dst, cursor, csr);

    k_prepw<<<(HC1c * F_INc + 48 * HC1c + 255) / 256, 256, 0, stream>>>(W1, W2, W1T, W2T);

    int nwave_blk = ((N_NODESc + 15) / 16 + 3) / 4;          // 1563
    k_gemm1<<<nwave_blk, 256, 0, stream>>>(x, W1T, as1w, ad1w, h1, a_s1, a_d1);
    k_agg1<<<(N_NODESc + 3) / 4, 256, 0, stream>>>(rowptr, csr, a_s1, a_d1, h1, b1, act1b);
    k_gemm2<<<nwave_blk, 256, 0, stream>>>(act1b, W2T, as2w, ad2w, h2b, a_s2, a_d2);
    k_agg2<<<(N_NODESc + 3) / 4, 256, 0, stream>>>(rowptr, csr, a_s2, a_d2, h2b, b2, out);
}

// Round 8
// 384.190 us; speedup vs baseline: 2.3587x; 1.1229x over previous
//
#include <hip/hip_runtime.h>
#include <hip/hip_fp16.h>
#include <math.h>

#define N_NODESc 100000
#define N_EDGESc 800000
#define E_TOTc   (N_EDGESc + N_NODESc)   // 900000, includes self loops
#define F_INc    128
#define HC1c     256                      // H1*C1
#define NCLSc    40
#define NEG_SLOPEc 0.2f

typedef _Float16 half8 __attribute__((ext_vector_type(8)));   // MFMA A/B frag
typedef __fp16   f16x2 __attribute__((ext_vector_type(2)));   // v_pk_* / cvt_pkrtz
typedef float    f32x4 __attribute__((ext_vector_type(4)));

__device__ __forceinline__ f16x2 shfl_xor_h2(f16x2 v, int mask) {
    union { f16x2 h; int i; } u; u.h = v;
    u.i = __shfl_xor(u.i, mask);
    return u.h;
}

// ---------------- CSR build ----------------

__global__ void k_count(const int* __restrict__ dst, int* cnt) {
    int e = blockIdx.x * blockDim.x + threadIdx.x;
    if (e < N_EDGESc) atomicAdd(&cnt[dst[e]], 1);
}

__global__ void k_scan1(const int* __restrict__ cnt, int* rowptr, int* bsums) {
    __shared__ int sh[512];
    int tid = threadIdx.x;
    int i = blockIdx.x * 512 + tid;
    int v = (i < N_NODESc) ? (cnt[i] + 1) : 0;   // +1 = self loop
    sh[tid] = v;
    __syncthreads();
    for (int off = 1; off < 512; off <<= 1) {
        int t = (tid >= off) ? sh[tid - off] : 0;
        __syncthreads();
        sh[tid] += t;
        __syncthreads();
    }
    if (i < N_NODESc) rowptr[i] = sh[tid] - v;
    if (tid == 511) bsums[blockIdx.x] = sh[511];
}

// one wave, shuffle prefix scan over nb (<=512) block sums
__global__ void k_scan2(int* bsums, int nb) {
    int L = threadIdx.x;          // 64 threads
    int run = 0;
    for (int s = 0; s < nb; s += 64) {
        int idx = s + L;
        int o = (idx < nb) ? bsums[idx] : 0;
        int v = o;
        #pragma unroll
        for (int off = 1; off < 64; off <<= 1) {
            int t = __shfl_up(v, off);
            if (L >= off) v += t;
        }
        int total = __shfl(v, 63);
        if (idx < nb) bsums[idx] = run + v - o;   // exclusive
        run += total;
    }
}

__global__ void k_scan3(int* rowptr, const int* __restrict__ bsums, int* cursor,
                        int* csr) {
    int i = blockIdx.x * blockDim.x + threadIdx.x;
    if (i < N_NODESc) {
        int rp = rowptr[i] + bsums[i >> 9];
        rowptr[i] = rp;
        cursor[i] = rp + 1;      // slot rp taken by the self loop
        csr[rp] = i;
    }
    if (i == 0) rowptr[N_NODESc] = E_TOTc;
}

__global__ void k_scatter(const int* __restrict__ src, const int* __restrict__ dst,
                          int* cursor, int* csr) {
    int t = blockIdx.x * blockDim.x + threadIdx.x;
    if (t < N_EDGESc) {
        int pos = atomicAdd(&cursor[dst[t]], 1);
        csr[pos] = src[t];
    }
}

// ---------------- prep: weights -> fp16 in MFMA B-fragment order -------------
// W1Tf: frag index f = (jt*4+k0)*64 + quad*16 + lane16, elems f*8+j.
//   Content = W1[k0*32+quad*8+j][lane16*16+jt]   (lambda col permutation:
//   accumulator (jt,lane16) then holds logical col lane16*16+jt).
// W2Tf: g = (jt*8+k0)*64 + quad*16 + lane16; content W2[k][jt*16+lane16].

__global__ void k_prepw(const float* __restrict__ W1, const float* __restrict__ W2,
                        _Float16* __restrict__ W1Tf, _Float16* __restrict__ W2Tf) {
    int f = blockIdx.x * 256 + threadIdx.x;
    if (f < 4096) {
        int lane16 = f & 15, quad = (f >> 4) & 3, k0 = (f >> 6) & 3, jt = f >> 8;
        int c = lane16 * 16 + jt;
        int kbase = k0 * 32 + quad * 8;
        _Float16* o = W1Tf + (size_t)f * 8;
        #pragma unroll
        for (int j = 0; j < 8; j++) o[j] = (_Float16)W1[(kbase + j) * HC1c + c];
    } else if (f < 4096 + 1536) {
        int g = f - 4096;
        int lane16 = g & 15, quad = (g >> 4) & 3, k0 = (g >> 6) & 7, jt = g >> 9;
        int c = jt * 16 + lane16;
        int kbase = k0 * 32 + quad * 8;
        _Float16* o = W2Tf + (size_t)g * 8;
        #pragma unroll
        for (int j = 0; j < 8; j++)
            o[j] = (c < NCLSc) ? (_Float16)W2[(kbase + j) * NCLSc + c] : (_Float16)0.f;
    }
}

// ---------------- Layer 1 GEMM (MFMA f16): h1 = f16(x) @ W1 ------------------
// B loads coalesced from fragment-order W1Tf; lane owns logical cols
// lane16*16..+15 -> h1 stored as 2 x uint4 per row; cheap alpha epilogue.

__global__ __launch_bounds__(256) void k_gemm1(
    const float* __restrict__ x, const _Float16* __restrict__ W1Tf,
    const float* __restrict__ a_src1, const float* __restrict__ a_dst1,
    _Float16* __restrict__ h1, float* __restrict__ as1, float* __restrict__ ad1) {
    int wave = (blockIdx.x * 256 + threadIdx.x) >> 6;
    int n0 = wave * 16;
    if (n0 >= N_NODESc) return;
    int L = threadIdx.x & 63, lane16 = L & 15, quad = L >> 4;
    f32x4 acc[16];
    #pragma unroll
    for (int jt = 0; jt < 16; jt++) acc[jt] = (f32x4){0.f, 0.f, 0.f, 0.f};
    const float* A = x + (size_t)(n0 + lane16) * F_INc + quad * 8;
    const _Float16* Bf = W1Tf + L * 8;
    #pragma unroll
    for (int k0 = 0; k0 < 4; k0++) {                         // K = 4 x 32
        float4 f0 = *(const float4*)(A + k0 * 32);
        float4 f1 = *(const float4*)(A + k0 * 32 + 4);
        union { half8 v; f16x2 h[4]; } af;
        af.h[0] = __builtin_amdgcn_cvt_pkrtz(f0.x, f0.y);
        af.h[1] = __builtin_amdgcn_cvt_pkrtz(f0.z, f0.w);
        af.h[2] = __builtin_amdgcn_cvt_pkrtz(f1.x, f1.y);
        af.h[3] = __builtin_amdgcn_cvt_pkrtz(f1.z, f1.w);
        #pragma unroll
        for (int jt = 0; jt < 16; jt++) {
            half8 bf = *(const half8*)(Bf + (jt * 4 + k0) * 512);
            acc[jt] = __builtin_amdgcn_mfma_f32_16x16x32_f16(af.v, bf, acc[jt], 0, 0, 0);
        }
    }
    // store: row n0+quad*4+r, logical cols lane16*16..+15 (contiguous)
    {
        size_t rowbase = (size_t)(n0 + quad * 4) * HC1c + lane16 * 16;
        #pragma unroll
        for (int r = 0; r < 4; r++) {
            union { uint4 u; f16x2 h[4]; } s0, s1;
            #pragma unroll
            for (int q = 0; q < 4; q++) {
                s0.h[q] = __builtin_amdgcn_cvt_pkrtz(acc[2 * q][r], acc[2 * q + 1][r]);
                s1.h[q] = __builtin_amdgcn_cvt_pkrtz(acc[8 + 2 * q][r], acc[9 + 2 * q][r]);
            }
            *(uint4*)(h1 + rowbase + (size_t)r * HC1c) = s0.u;
            *(uint4*)(h1 + rowbase + (size_t)r * HC1c + 8) = s1.u;
        }
    }
    // alpha epilogue: lane's 16 cols all in head lane16>>1
    {
        float asv[16], adv[16];
        const float4* ap = (const float4*)(a_src1 + lane16 * 16);
        const float4* dp = (const float4*)(a_dst1 + lane16 * 16);
        #pragma unroll
        for (int q = 0; q < 4; q++) {
            float4 a4 = ap[q], d4 = dp[q];
            asv[4*q] = a4.x; asv[4*q+1] = a4.y; asv[4*q+2] = a4.z; asv[4*q+3] = a4.w;
            adv[4*q] = d4.x; adv[4*q+1] = d4.y; adv[4*q+2] = d4.z; adv[4*q+3] = d4.w;
        }
        float ps[4] = {0,0,0,0}, pd[4] = {0,0,0,0};
        #pragma unroll
        for (int jt = 0; jt < 16; jt++) {
            #pragma unroll
            for (int r = 0; r < 4; r++) {
                ps[r] += acc[jt][r] * asv[jt];
                pd[r] += acc[jt][r] * adv[jt];
            }
        }
        #pragma unroll
        for (int r = 0; r < 4; r++) {
            ps[r] += __shfl_xor(ps[r], 1);
            pd[r] += __shfl_xor(pd[r], 1);
        }
        if ((lane16 & 1) == 0) {
            int h = lane16 >> 1;
            #pragma unroll
            for (int r = 0; r < 4; r++) {
                int n = n0 + quad * 4 + r;
                as1[n * 8 + h] = ps[r];
                ad1[n * 8 + h] = pd[r];
            }
        }
    }
}

// ---------------- Layer 1 aggregation: wave-per-node, CHUNK=16, batched MLP ---

__global__ __launch_bounds__(256) void k_agg1(
    const int* __restrict__ rowptr, const int* __restrict__ csr,
    const float* __restrict__ as1, const float* __restrict__ ad1,
    const _Float16* __restrict__ h1, const float* __restrict__ b1,
    _Float16* __restrict__ act1b) {
    int n = blockIdx.x * 4 + (threadIdx.x >> 6);
    if (n >= N_NODESc) return;
    int L = threadIdx.x & 63;
    int eL = L >> 3, hL = L & 7;
    int half = L >> 5, l32 = L & 31;
    int hA = l32 >> 2;
    int beg = rowptr[n], end = rowptr[n + 1];
    float ad = ad1[n * 8 + hL];
    float m_run = -INFINITY, d_run = 0.f;
    f16x2 acc4[4];
    #pragma unroll
    for (int q = 0; q < 4; q++) acc4[q] = (f16x2){(__fp16)0.f, (__fp16)0.f};
    for (int base = beg; base < end; base += 16) {
        int m = min(16, end - base);
        int src0 = 0, src1 = 0;
        float s0 = -INFINITY, s1 = -INFINITY;
        if (eL < m) {
            src0 = csr[base + eL];
            float v = as1[src0 * 8 + hL] + ad;
            s0 = (v > 0.f) ? v : NEG_SLOPEc * v;
        }
        if (eL + 8 < m) {
            src1 = csr[base + eL + 8];
            float v = as1[src1 * 8 + hL] + ad;
            s1 = (v > 0.f) ? v : NEG_SLOPEc * v;
        }
        float mc = fmaxf(s0, s1);
        mc = fmaxf(mc, __shfl_xor(mc, 8));
        mc = fmaxf(mc, __shfl_xor(mc, 16));
        mc = fmaxf(mc, __shfl_xor(mc, 32));
        float mnew = fmaxf(m_run, mc);
        float w0 = (eL < m) ? __expf(s0 - mnew) : 0.f;
        float w1 = (eL + 8 < m) ? __expf(s1 - mnew) : 0.f;
        float wsum = w0 + w1;
        wsum += __shfl_xor(wsum, 8);
        wsum += __shfl_xor(wsum, 16);
        wsum += __shfl_xor(wsum, 32);
        float scale = __expf(m_run - mnew);
        d_run = d_run * scale + wsum;
        m_run = mnew;
        float sc = __shfl(scale, hA);
        f16x2 sc2 = __builtin_amdgcn_cvt_pkrtz(sc, sc);
        #pragma unroll
        for (int q = 0; q < 4; q++) acc4[q] *= sc2;
        {
            float we[4]; int se[4]; uint4 pk[4];
            #pragma unroll
            for (int j = 0; j < 4; j++) {
                int e = 2 * j + half;
                we[j] = __shfl(w0, e * 8 + hA);
                se[j] = __shfl(src0, e * 8 + hA);
            }
            #pragma unroll
            for (int j = 0; j < 4; j++) {
                int e = 2 * j + half;
                pk[j] = (uint4){0u, 0u, 0u, 0u};
                if (e < m) pk[j] = *((const uint4*)(h1 + (size_t)se[j] * HC1c) + l32);
            }
            #pragma unroll
            for (int j = 0; j < 4; j++) {
                f16x2 we2 = __builtin_amdgcn_cvt_pkrtz(we[j], we[j]);
                union { uint4 u; f16x2 h[4]; } pp; pp.u = pk[j];
                acc4[0] += we2 * pp.h[0];
                acc4[1] += we2 * pp.h[1];
                acc4[2] += we2 * pp.h[2];
                acc4[3] += we2 * pp.h[3];
            }
        }
        if (m > 8) {
            float we[4]; int se[4]; uint4 pk[4];
            #pragma unroll
            for (int j = 0; j < 4; j++) {
                int el = 2 * j + half;
                we[j] = __shfl(w1, el * 8 + hA);
                se[j] = __shfl(src1, el * 8 + hA);
            }
            #pragma unroll
            for (int j = 0; j < 4; j++) {
                int e = 8 + 2 * j + half;
                pk[j] = (uint4){0u, 0u, 0u, 0u};
                if (e < m) pk[j] = *((const uint4*)(h1 + (size_t)se[j] * HC1c) + l32);
            }
            #pragma unroll
            for (int j = 0; j < 4; j++) {
                f16x2 we2 = __builtin_amdgcn_cvt_pkrtz(we[j], we[j]);
                union { uint4 u; f16x2 h[4]; } pp; pp.u = pk[j];
                acc4[0] += we2 * pp.h[0];
                acc4[1] += we2 * pp.h[1];
                acc4[2] += we2 * pp.h[2];
                acc4[3] += we2 * pp.h[3];
            }
        }
    }
    float inv = 1.f / (d_run + 1e-16f);
    float inv_h = __shfl(inv, hA);
    #pragma unroll
    for (int q = 0; q < 4; q++) acc4[q] += shfl_xor_h2(acc4[q], 32);
    if (half == 0) {
        float4 b0 = ((const float4*)b1)[l32 * 2];
        float4 b4 = ((const float4*)b1)[l32 * 2 + 1];
        float o[8];
        o[0] = (float)acc4[0][0] * inv_h + b0.x; o[1] = (float)acc4[0][1] * inv_h + b0.y;
        o[2] = (float)acc4[1][0] * inv_h + b0.z; o[3] = (float)acc4[1][1] * inv_h + b0.w;
        o[4] = (float)acc4[2][0] * inv_h + b4.x; o[5] = (float)acc4[2][1] * inv_h + b4.y;
        o[6] = (float)acc4[3][0] * inv_h + b4.z; o[7] = (float)acc4[3][1] * inv_h + b4.w;
        #pragma unroll
        for (int j = 0; j < 8; j++) o[j] = (o[j] > 0.f) ? o[j] : expm1f(o[j]);
        union { uint4 u; f16x2 h[4]; } st;
        st.h[0] = __builtin_amdgcn_cvt_pkrtz(o[0], o[1]);
        st.h[1] = __builtin_amdgcn_cvt_pkrtz(o[2], o[3]);
        st.h[2] = __builtin_amdgcn_cvt_pkrtz(o[4], o[5]);
        st.h[3] = __builtin_amdgcn_cvt_pkrtz(o[6], o[7]);
        *((uint4*)(act1b + (size_t)n * HC1c) + l32) = st.u;
    }
}

// ---------------- Layer 2 GEMM (MFMA f16) + fused alpha2; h2 out = fp16 ------

__global__ __launch_bounds__(256) void k_gemm2(
    const _Float16* __restrict__ act1b, const _Float16* __restrict__ W2Tf,
    const float* __restrict__ a_src2, const float* __restrict__ a_dst2,
    _Float16* __restrict__ h2b, float* __restrict__ as2, float* __restrict__ ad2) {
    int wave = (blockIdx.x * 256 + threadIdx.x) >> 6;
    int n0 = wave * 16;
    if (n0 >= N_NODESc) return;
    int L = threadIdx.x & 63, lane16 = L & 15, quad = L >> 4;
    f32x4 acc[3];
    #pragma unroll
    for (int jt = 0; jt < 3; jt++) acc[jt] = (f32x4){0.f, 0.f, 0.f, 0.f};
    const _Float16* A = act1b + (size_t)(n0 + lane16) * HC1c + quad * 8;
    const _Float16* Bf = W2Tf + L * 8;
    #pragma unroll
    for (int k0 = 0; k0 < 8; k0++) {                         // K = 8 x 32
        half8 af = *(const half8*)(A + k0 * 32);
        #pragma unroll
        for (int jt = 0; jt < 3; jt++) {
            half8 bf = *(const half8*)(Bf + (jt * 8 + k0) * 512);
            acc[jt] = __builtin_amdgcn_mfma_f32_16x16x32_f16(af, bf, acc[jt], 0, 0, 0);
        }
    }
    float ps[4] = {0.f, 0.f, 0.f, 0.f}, pd[4] = {0.f, 0.f, 0.f, 0.f};
    #pragma unroll
    for (int jt = 0; jt < 3; jt++) {
        int col = jt * 16 + lane16;
        float ws = (col < NCLSc) ? a_src2[col] : 0.f;
        float wd = (col < NCLSc) ? a_dst2[col] : 0.f;
        #pragma unroll
        for (int r = 0; r < 4; r++) {
            float v = acc[jt][r];
            int n = n0 + quad * 4 + r;
            if (col < NCLSc) h2b[(size_t)n * NCLSc + col] = (_Float16)v;
            ps[r] += v * ws; pd[r] += v * wd;
        }
    }
    #pragma unroll
    for (int r = 0; r < 4; r++) {
        float s = ps[r], d = pd[r];
        s += __shfl_xor(s, 1); d += __shfl_xor(d, 1);
        s += __shfl_xor(s, 2); d += __shfl_xor(d, 2);
        s += __shfl_xor(s, 4); d += __shfl_xor(d, 4);
        s += __shfl_xor(s, 8); d += __shfl_xor(d, 8);
        if (lane16 == 0) {
            int n = n0 + quad * 4 + r;
            as2[n] = s; ad2[n] = d;
        }
    }
}

// ---------------- Layer 2 aggregation + bias + log_softmax: wave-per-node ----

__global__ __launch_bounds__(256) void k_agg2(
    const int* __restrict__ rowptr, const int* __restrict__ csr,
    const float* __restrict__ as2, const float* __restrict__ ad2,
    const _Float16* __restrict__ h2b, const float* __restrict__ b2,
    float* __restrict__ out) {
    int n = blockIdx.x * 4 + (threadIdx.x >> 6);
    if (n >= N_NODESc) return;
    int L = threadIdx.x & 63;
    int g = L / 20, cls = L % 20;        // g==3 for lanes 60..63 (gather-idle)
    int beg = rowptr[n], end = rowptr[n + 1];
    float ad = ad2[n];
    float m_run = -INFINITY, d_run = 0.f;
    f16x2 acc2 = (f16x2){(__fp16)0.f, (__fp16)0.f};
    for (int base = beg; base < end; base += 64) {
        int m = min(64, end - base);
        int src = 0; float s = -INFINITY;
        if (L < m) {
            src = csr[base + L];
            float v = as2[src] + ad;
            s = (v > 0.f) ? v : NEG_SLOPEc * v;
        }
        float mc = s;
        for (int o = 32; o; o >>= 1) mc = fmaxf(mc, __shfl_xor(mc, o));
        float mnew = fmaxf(m_run, mc);
        float w = (L < m) ? __expf(s - mnew) : 0.f;
        float ws = w;
        for (int o = 32; o; o >>= 1) ws += __shfl_xor(ws, o);
        float scale = __expf(m_run - mnew);
        d_run = d_run * scale + ws;
        m_run = mnew;
        f16x2 sc2 = __builtin_amdgcn_cvt_pkrtz(scale, scale);
        acc2 *= sc2;
        for (int j = 0; j < m; j += 3) {
            int e = j + g;
            int lane = (e < 64) ? e : 63;
            float we = __shfl(w, lane);
            int  se = __shfl(src, lane);
            if (g < 3 && e < m) {
                f16x2 we2 = __builtin_amdgcn_cvt_pkrtz(we, we);
                union { unsigned u; f16x2 h; } pk;
                pk.u = *((const unsigned*)(h2b + (size_t)se * NCLSc) + cls);
                acc2 += we2 * pk.h;
            }
        }
    }
    union { f16x2 h; int i; } au; au.h = acc2;
    int i1 = __shfl(au.i, (L + 20) & 63);
    int i2 = __shfl(au.i, (L + 40) & 63);
    union { int i; f16x2 h; } b1u, b2u; b1u.i = i1; b2u.i = i2;
    acc2 = acc2 + b1u.h + b2u.h;
    float vx = -INFINITY, vy = -INFINITY;
    if (L < 20) {
        float2 bb = ((const float2*)b2)[L];
        float inv = 1.f / (d_run + 1e-16f);
        vx = (float)acc2[0] * inv + bb.x;
        vy = (float)acc2[1] * inv + bb.y;
    }
    float mv = fmaxf(vx, vy);
    for (int o = 32; o; o >>= 1) mv = fmaxf(mv, __shfl_xor(mv, o));
    float ex = (L < 20) ? __expf(vx - mv) + __expf(vy - mv) : 0.f;
    for (int o = 32; o; o >>= 1) ex += __shfl_xor(ex, o);
    float ls = logf(ex);
    if (L < 20) {
        float2 o2; o2.x = vx - mv - ls; o2.y = vy - mv - ls;
        ((float2*)(out + (size_t)n * NCLSc))[L] = o2;
    }
}

// ---------------- launch ----------------

extern "C" void kernel_launch(void* const* d_in, const int* in_sizes, int n_in,
                              void* d_out, int out_size, void* d_ws, size_t ws_size,
                              hipStream_t stream) {
    const float* x    = (const float*)d_in[0];
    const int*   ei   = (const int*)d_in[1];
    const float* W1   = (const float*)d_in[2];
    const float* as1w = (const float*)d_in[3];
    const float* ad1w = (const float*)d_in[4];
    const float* b1   = (const float*)d_in[5];
    const float* W2   = (const float*)d_in[6];
    const float* as2w = (const float*)d_in[7];
    const float* ad2w = (const float*)d_in[8];
    const float* b2   = (const float*)d_in[9];
    float* out = (float*)d_out;

    char* p = (char*)d_ws;
    _Float16* h1    = (_Float16*)p; p += (size_t)N_NODESc * HC1c * 2;
    _Float16* act1b = (_Float16*)p; p += (size_t)N_NODESc * HC1c * 2;
    _Float16* W1Tf  = (_Float16*)p; p += (size_t)4096 * 8 * 2;   // 64 KB
    _Float16* W2Tf  = (_Float16*)p; p += (size_t)1536 * 8 * 2;   // 24 KB
    float* a_s1 = (float*)p; p += (size_t)N_NODESc * 8 * 4;
    float* a_d1 = (float*)p; p += (size_t)N_NODESc * 8 * 4;
    _Float16* h2b = (_Float16*)p; p += (size_t)N_NODESc * NCLSc * 2;
    float* a_s2 = (float*)p; p += (size_t)N_NODESc * 4;
    float* a_d2 = (float*)p; p += (size_t)N_NODESc * 4;
    int* rowptr = (int*)p;   p += (size_t)(N_NODESc + 1) * 4;
    int* cursor = (int*)p;   p += (size_t)N_NODESc * 4;
    int* bsums  = (int*)p;   p += 512 * 4;
    int* csr    = (int*)p;   p += (size_t)E_TOTc * 4;
    (void)ws_size; (void)in_sizes; (void)n_in; (void)out_size;

    const int* src = ei;
    const int* dst = ei + N_EDGESc;

    // CSR build (self loops folded into scan; cursor doubles as count buffer)
    (void)hipMemsetAsync(cursor, 0, (size_t)N_NODESc * 4, stream);
    k_count<<<(N_EDGESc + 255) / 256, 256, 0, stream>>>(dst, cursor);
    int nb = (N_NODESc + 511) / 512;
    k_scan1<<<nb, 512, 0, stream>>>(cursor, rowptr, bsums);
    k_scan2<<<1, 64, 0, stream>>>(bsums, nb);
    k_scan3<<<(N_NODESc + 255) / 256, 256, 0, stream>>>(rowptr, bsums, cursor, csr);
    k_scatter<<<(N_EDGESc + 255) / 256, 256, 0, stream>>>(src, dst, cursor, csr);

    k_prepw<<<22, 256, 0, stream>>>(W1, W2, W1Tf, W2Tf);

    int nwave_blk = ((N_NODESc + 15) / 16 + 3) / 4;          // 1563
    k_gemm1<<<nwave_blk, 256, 0, stream>>>(x, W1Tf, as1w, ad1w, h1, a_s1, a_d1);
    k_agg1<<<(N_NODESc + 3) / 4, 256, 0, stream>>>(rowptr, csr, a_s1, a_d1, h1, b1, act1b);
    k_gemm2<<<nwave_blk, 256, 0, stream>>>(act1b, W2Tf, as2w, ad2w, h2b, a_s2, a_d2);
    k_agg2<<<(N_NODESc + 3) / 4, 256, 0, stream>>>(rowptr, csr, a_s2, a_d2, h2b, b2, out);
}